// Round 1
// baseline (1679.189 us; speedup 1.0000x reference)
//
#include <hip/hip_runtime.h>

#define NNODES 100000
#define NEDGES 1600000
#define NGRAPH 512
#define DIM    100
#define DP     128
#define EPSBN  1e-5f

// ---------------- degree histogram ----------------
__global__ void hist_kernel(const int* __restrict__ dst, int* __restrict__ hist, int e) {
    int i = blockIdx.x * blockDim.x + threadIdx.x;
    if (i < e) atomicAdd(&hist[dst[i]], 1);
}

// ---------------- dinv (with and without self loops) ----------------
__global__ void dinv_kernel(const int* __restrict__ hist, float* __restrict__ dsl,
                            float* __restrict__ dnsl, int n) {
    int i = blockIdx.x * blockDim.x + threadIdx.x;
    if (i >= n) return;
    float c = (float)hist[i];
    dsl[i]  = rsqrtf(c + 1.0f);
    dnsl[i] = (c > 0.0f) ? rsqrtf(c) : 0.0f;
}

// ---------------- two-level exclusive scan over hist (256/block) ----------------
__global__ void scan1_kernel(const int* __restrict__ hist, int* __restrict__ off,
                             int* __restrict__ partials, int n) {
    __shared__ int s[256];
    int i = blockIdx.x * 256 + threadIdx.x;
    int v = (i < n) ? hist[i] : 0;
    s[threadIdx.x] = v; __syncthreads();
    for (int o = 1; o < 256; o <<= 1) {
        int t = (threadIdx.x >= o) ? s[threadIdx.x - o] : 0;
        __syncthreads();
        s[threadIdx.x] += t;
        __syncthreads();
    }
    if (i < n) off[i] = s[threadIdx.x] - v;      // block-local exclusive
    if (threadIdx.x == 255) partials[blockIdx.x] = s[255];
}

__global__ void scan2_kernel(int* __restrict__ partials, int nb) {
    __shared__ int s[512];
    int v = (threadIdx.x < nb) ? partials[threadIdx.x] : 0;
    s[threadIdx.x] = v; __syncthreads();
    for (int o = 1; o < 512; o <<= 1) {
        int t = (threadIdx.x >= o) ? s[threadIdx.x - o] : 0;
        __syncthreads();
        s[threadIdx.x] += t;
        __syncthreads();
    }
    if (threadIdx.x < nb) partials[threadIdx.x] = s[threadIdx.x] - v;  // exclusive
}

__global__ void scan3_kernel(int* __restrict__ off, const int* __restrict__ partials,
                             int* __restrict__ cursor, int n, int e_total) {
    int i = blockIdx.x * 256 + threadIdx.x;
    if (i < n) {
        int v = off[i] + partials[blockIdx.x];
        off[i] = v;
        cursor[i] = v;
    }
    if (i == 0) off[n] = e_total;
}

// ---------------- scatter edges into CSR-by-dst ----------------
__global__ void scatter_kernel(const int* __restrict__ src, const int* __restrict__ dst,
                               int* __restrict__ cursor, int* __restrict__ ssorted, int e) {
    int i = blockIdx.x * blockDim.x + threadIdx.x;
    if (i < e) {
        int p = atomicAdd(&cursor[dst[i]], 1);
        ssorted[p] = src[i];
    }
}

// ---------------- propagation: one wave per node ----------------
// out[n,:] = dinv[n] * sum_e dinv[src_e] * x[src_e,:]  (+ selfloop: x[n,:]*dinv[n]^2)
__global__ __launch_bounds__(256) void prop_kernel(
        const float* __restrict__ xin, const int* __restrict__ ssorted,
        const int* __restrict__ off, const float* __restrict__ dinv,
        float* __restrict__ out, int n, int selfloop) {
    int wave = (blockIdx.x * blockDim.x + threadIdx.x) >> 6;
    int lane = threadIdx.x & 63;
    if (wave >= n) return;
    int e0 = off[wave], e1 = off[wave + 1];
    float ax = 0.0f, ay = 0.0f;
    for (int e = e0; e < e1; ++e) {
        int s = ssorted[e];
        float ds = dinv[s];
        float2 v = *(const float2*)&xin[(long)s * DP + lane * 2];
        ax += ds * v.x;
        ay += ds * v.y;
    }
    float dn = dinv[wave];
    float rx = dn * ax, ry = dn * ay;
    if (selfloop) {
        float2 v = *(const float2*)&xin[(long)wave * DP + lane * 2];
        float d2 = dn * dn;
        rx += d2 * v.x;
        ry += d2 * v.y;
    }
    float2 r; r.x = rx; r.y = ry;
    *(float2*)&out[(long)wave * DP + lane * 2] = r;
}

// ---------------- node-level matmul: C[M,128] = op(A[M,128(K used)] @ W[K,Kout] (+bias)(+addend), relu) ----------------
__global__ __launch_bounds__(256) void matmul_kernel(
        const float* __restrict__ A, const float* __restrict__ W,
        const float* __restrict__ bias, const float* __restrict__ addend,
        float* __restrict__ C, int M, int K, int Kout, int relu) {
    extern __shared__ float Wl[];   // K * 128, Kout..127 zero-padded
    int tid = threadIdx.x;
    int total = K * DP;
    for (int idx = tid; idx < total; idx += 256) {
        int k = idx >> 7, c = idx & 127;
        Wl[idx] = (c < Kout) ? W[k * Kout + c] : 0.0f;
    }
    __syncthreads();

    int colg = tid & 31;       // 32 col-groups of 4
    int rowg = tid >> 5;       // 8 row-groups of 8
    long row0 = (long)blockIdx.x * 64 + rowg * 8;
    int c0 = colg * 4;

    float4 acc[8];
    long r[8];
#pragma unroll
    for (int i = 0; i < 8; i++) {
        acc[i] = make_float4(0.f, 0.f, 0.f, 0.f);
        long rr = row0 + i;
        r[i] = (rr < M) ? rr : (long)(M - 1);
    }

    for (int k = 0; k < K; k += 4) {
        float4 w0 = *(const float4*)&Wl[(k + 0) * DP + c0];
        float4 w1 = *(const float4*)&Wl[(k + 1) * DP + c0];
        float4 w2 = *(const float4*)&Wl[(k + 2) * DP + c0];
        float4 w3 = *(const float4*)&Wl[(k + 3) * DP + c0];
#pragma unroll
        for (int i = 0; i < 8; i++) {
            float4 a4 = *(const float4*)&A[r[i] * DP + k];
            acc[i].x += a4.x * w0.x + a4.y * w1.x + a4.z * w2.x + a4.w * w3.x;
            acc[i].y += a4.x * w0.y + a4.y * w1.y + a4.z * w2.y + a4.w * w3.y;
            acc[i].z += a4.x * w0.z + a4.y * w1.z + a4.z * w2.z + a4.w * w3.z;
            acc[i].w += a4.x * w0.w + a4.y * w1.w + a4.z * w2.w + a4.w * w3.w;
        }
    }

    float4 bv = make_float4(0.f, 0.f, 0.f, 0.f);
    if (bias && c0 < Kout) bv = *(const float4*)&bias[c0];

#pragma unroll
    for (int i = 0; i < 8; i++) {
        long rr = row0 + i;
        if (rr >= M) break;
        float4 v = acc[i];
        v.x += bv.x; v.y += bv.y; v.z += bv.z; v.w += bv.w;
        if (addend) {
            float4 ad = *(const float4*)&addend[rr * DP + c0];
            v.x += ad.x; v.y += ad.y; v.z += ad.z; v.w += ad.w;
        }
        if (relu) {
            v.x = fmaxf(v.x, 0.f); v.y = fmaxf(v.y, 0.f);
            v.z = fmaxf(v.z, 0.f); v.w = fmaxf(v.w, 0.f);
        }
        *(float4*)&C[rr * DP + c0] = v;
    }
}

// ---------------- batchnorm stats ----------------
__global__ void bn_stats_kernel(const float* __restrict__ h, float* __restrict__ sum,
                                float* __restrict__ sq, int n) {
    int col = threadIdx.x;   // 128 threads
    float s = 0.f, q = 0.f;
    for (int row = blockIdx.x; row < n; row += gridDim.x) {
        float v = h[(long)row * DP + col];
        s += v;
        q += v * v;
    }
    atomicAdd(&sum[col], s);
    atomicAdd(&sq[col], q);
}

__global__ void bn_apply_kernel(float* __restrict__ h, const float* __restrict__ sum,
                                const float* __restrict__ sq, const float* __restrict__ gamma,
                                const float* __restrict__ beta, int n) {
    long i = (long)blockIdx.x * blockDim.x + threadIdx.x;
    if (i >= (long)n * DP) return;
    int c = (int)(i & 127);
    if (c >= DIM) return;
    float inv_n = 1.0f / (float)n;
    float mu = sum[c] * inv_n;
    float var = sq[c] * inv_n - mu * mu;
    float rs = rsqrtf(var + EPSBN);
    h[i] = (h[i] - mu) * rs * gamma[c] + beta[c];
}

// ---------------- global add pool ----------------
__global__ void pool_kernel(const float* __restrict__ a, const int* __restrict__ batch,
                            float* __restrict__ g, int n) {
    long t = (long)blockIdx.x * blockDim.x + threadIdx.x;
    int node = (int)(t >> 5);
    int c4 = (int)(t & 31);
    if (node >= n || c4 >= 25) return;   // 25*4 = 100 features
    int b = batch[node];
    float4 v = *(const float4*)&a[(long)node * DP + c4 * 4];
    atomicAdd(&g[b * DP + c4 * 4 + 0], v.x);
    atomicAdd(&g[b * DP + c4 * 4 + 1], v.y);
    atomicAdd(&g[b * DP + c4 * 4 + 2], v.z);
    atomicAdd(&g[b * DP + c4 * 4 + 3], v.w);
}

// ---------------- fused MLP head: one block per graph ----------------
__global__ __launch_bounds__(256) void mlp_kernel(
        const float* __restrict__ g,
        const float* __restrict__ Wf1, const float* __restrict__ bf1,
        const float* __restrict__ Wf2, const float* __restrict__ bf2,
        const float* __restrict__ Wf3, const float* __restrict__ bf3,
        const float* __restrict__ Wf4, const float* __restrict__ bf4,
        float* __restrict__ out) {
    __shared__ float a0[100], a1[200], a2[300], a3[200], red[256];
    int b = blockIdx.x, tid = threadIdx.x;
    if (tid < 100) a0[tid] = g[b * DP + tid];
    __syncthreads();
    for (int c = tid; c < 200; c += 256) {
        float s = bf1[c];
        for (int k = 0; k < 100; k++) s += a0[k] * Wf1[k * 200 + c];
        a1[c] = fmaxf(s, 0.f);
    }
    __syncthreads();
    for (int c = tid; c < 300; c += 256) {
        float s = bf2[c];
        for (int k = 0; k < 200; k++) s += a1[k] * Wf2[k * 300 + c];
        a2[c] = fmaxf(s, 0.f);
    }
    __syncthreads();
    for (int c = tid; c < 200; c += 256) {
        float s = bf3[c];
        for (int k = 0; k < 300; k++) s += a2[k] * Wf3[k * 200 + c];
        a3[c] = fmaxf(s, 0.f);
    }
    __syncthreads();
    red[tid] = (tid < 200) ? a3[tid] * Wf4[tid] : 0.f;
    __syncthreads();
    for (int o = 128; o > 0; o >>= 1) {
        if (tid < o) red[tid] += red[tid + o];
        __syncthreads();
    }
    if (tid == 0) out[b] = red[0] + bf4[0];
}

extern "C" void kernel_launch(void* const* d_in, const int* in_sizes, int n_in,
                              void* d_out, int out_size, void* d_ws, size_t ws_size,
                              hipStream_t stream) {
    const float* x      = (const float*)d_in[0];
    const int*   src    = (const int*)d_in[1];
    const int*   dst    = (const int*)d_in[2];
    const int*   batch  = (const int*)d_in[3];
    const float* W1     = (const float*)d_in[4];
    const float* b1     = (const float*)d_in[5];
    const float* W2     = (const float*)d_in[6];
    const float* b2     = (const float*)d_in[7];
    const float* gamma  = (const float*)d_in[8];
    const float* beta   = (const float*)d_in[9];
    const float* Wa_init= (const float*)d_in[10];
    const float* Wa_root= (const float*)d_in[11];
    const float* ba     = (const float*)d_in[12];
    const float* Wf1    = (const float*)d_in[13];
    const float* bf1    = (const float*)d_in[14];
    const float* Wf2    = (const float*)d_in[15];
    const float* bf2    = (const float*)d_in[16];
    const float* Wf3    = (const float*)d_in[17];
    const float* bf3    = (const float*)d_in[18];
    const float* Wf4    = (const float*)d_in[19];
    const float* bf4    = (const float*)d_in[20];
    float* out = (float*)d_out;

    const int n = NNODES;
    const int e = NEDGES;

    // ---- workspace carve (all 256B aligned) ----
    char* ws = (char*)d_ws;
    auto carve = [&](size_t bytes) -> void* {
        void* p = (void*)ws;
        ws += (bytes + 255) & ~(size_t)255;
        return p;
    };
    float* bufA    = (float*)carve((size_t)n * DP * 4);
    float* bufB    = (float*)carve((size_t)n * DP * 4);
    float* bufC    = (float*)carve((size_t)n * DP * 4);
    int*   hist    = (int*)carve((size_t)n * 4);
    int*   off     = (int*)carve((size_t)(n + 1) * 4);
    int*   cursor  = (int*)carve((size_t)n * 4);
    int*   partials= (int*)carve(512 * 4);
    int*   ssorted = (int*)carve((size_t)e * 4);
    float* dinv_sl = (float*)carve((size_t)n * 4);
    float* dinv_nsl= (float*)carve((size_t)n * 4);
    float* bnsum   = (float*)carve(DP * 4);
    float* bnsq    = (float*)carve(DP * 4);
    float* gpool   = (float*)carve((size_t)NGRAPH * DP * 4);

    const int nb = (n + 255) / 256;   // 391 scan blocks

    // ---- build CSR by dst ----
    hipMemsetAsync(hist, 0, (size_t)n * 4, stream);
    hist_kernel<<<(e + 255) / 256, 256, 0, stream>>>(dst, hist, e);
    dinv_kernel<<<(n + 255) / 256, 256, 0, stream>>>(hist, dinv_sl, dinv_nsl, n);
    scan1_kernel<<<nb, 256, 0, stream>>>(hist, off, partials, n);
    scan2_kernel<<<1, 512, 0, stream>>>(partials, nb);
    scan3_kernel<<<nb, 256, 0, stream>>>(off, partials, cursor, n, e);
    scatter_kernel<<<(e + 255) / 256, 256, 0, stream>>>(src, dst, cursor, ssorted, e);

    const int prop_blocks = (n + 3) / 4;   // 4 waves per 256-thread block

    // ---- SGConv 1: prop(x, self-loops) @ W1 + b1, relu ----
    prop_kernel<<<prop_blocks, 256, 0, stream>>>(x, ssorted, off, dinv_sl, bufA, n, 1);
    matmul_kernel<<<(n + 63) / 64, 256, 128 * DP * 4, stream>>>(bufA, W1, b1, nullptr, bufB, n, 128, DIM, 1);

    // ---- SGConv 2 ----
    prop_kernel<<<prop_blocks, 256, 0, stream>>>(bufB, ssorted, off, dinv_sl, bufA, n, 1);
    matmul_kernel<<<(n + 63) / 64, 256, DIM * DP * 4, stream>>>(bufA, W2, b2, nullptr, bufB, n, DIM, DIM, 1);

    // ---- BatchNorm (training stats) ----
    hipMemsetAsync(bnsum, 0, DP * 4, stream);
    hipMemsetAsync(bnsq, 0, DP * 4, stream);
    bn_stats_kernel<<<512, 128, 0, stream>>>(bufB, bnsum, bnsq, n);
    bn_apply_kernel<<<(int)(((long)n * DP + 255) / 256), 256, 0, stream>>>(bufB, bnsum, bnsq, gamma, beta, n);

    // ---- ARMAConv: relu(prop(h @ Wa_init, no self-loops) + h @ Wa_root + ba) ----
    matmul_kernel<<<(n + 63) / 64, 256, DIM * DP * 4, stream>>>(bufB, Wa_init, nullptr, nullptr, bufA, n, DIM, DIM, 0);
    prop_kernel<<<prop_blocks, 256, 0, stream>>>(bufA, ssorted, off, dinv_nsl, bufC, n, 0);
    matmul_kernel<<<(n + 63) / 64, 256, DIM * DP * 4, stream>>>(bufB, Wa_root, ba, bufC, bufA, n, DIM, DIM, 1);

    // ---- global add pool ----
    hipMemsetAsync(gpool, 0, (size_t)NGRAPH * DP * 4, stream);
    pool_kernel<<<(int)(((long)n * 32 + 255) / 256), 256, 0, stream>>>(bufA, batch, gpool, n);

    // ---- MLP head ----
    mlp_kernel<<<NGRAPH, 256, 0, stream>>>(gpool, Wf1, bf1, Wf2, bf2, Wf3, bf3, Wf4, bf4, out);
}

// Round 2
// 1524.529 us; speedup vs baseline: 1.1014x; 1.1014x over previous
//
#include <hip/hip_runtime.h>

#define NNODES 100000
#define NEDGES 1600000
#define NGRAPH 512
#define DIM    100
#define DP     128
#define EPSBN  1e-5f

// ---------------- degree histogram ----------------
__global__ void hist_kernel(const int* __restrict__ dst, int* __restrict__ hist, int e) {
    int i = blockIdx.x * blockDim.x + threadIdx.x;
    if (i < e) atomicAdd(&hist[dst[i]], 1);
}

// ---------------- dinv (with and without self loops) ----------------
__global__ void dinv_kernel(const int* __restrict__ hist, float* __restrict__ dsl,
                            float* __restrict__ dnsl, int n) {
    int i = blockIdx.x * blockDim.x + threadIdx.x;
    if (i >= n) return;
    float c = (float)hist[i];
    dsl[i]  = rsqrtf(c + 1.0f);
    dnsl[i] = (c > 0.0f) ? rsqrtf(c) : 0.0f;
}

// ---------------- two-level exclusive scan over hist (256/block) ----------------
__global__ void scan1_kernel(const int* __restrict__ hist, int* __restrict__ off,
                             int* __restrict__ partials, int n) {
    __shared__ int s[256];
    int i = blockIdx.x * 256 + threadIdx.x;
    int v = (i < n) ? hist[i] : 0;
    s[threadIdx.x] = v; __syncthreads();
    for (int o = 1; o < 256; o <<= 1) {
        int t = (threadIdx.x >= o) ? s[threadIdx.x - o] : 0;
        __syncthreads();
        s[threadIdx.x] += t;
        __syncthreads();
    }
    if (i < n) off[i] = s[threadIdx.x] - v;      // block-local exclusive
    if (threadIdx.x == 255) partials[blockIdx.x] = s[255];
}

__global__ void scan2_kernel(int* __restrict__ partials, int nb) {
    __shared__ int s[512];
    int v = (threadIdx.x < nb) ? partials[threadIdx.x] : 0;
    s[threadIdx.x] = v; __syncthreads();
    for (int o = 1; o < 512; o <<= 1) {
        int t = (threadIdx.x >= o) ? s[threadIdx.x - o] : 0;
        __syncthreads();
        s[threadIdx.x] += t;
        __syncthreads();
    }
    if (threadIdx.x < nb) partials[threadIdx.x] = s[threadIdx.x] - v;  // exclusive
}

__global__ void scan3_kernel(int* __restrict__ off, const int* __restrict__ partials,
                             int* __restrict__ cursor, int n, int e_total) {
    int i = blockIdx.x * 256 + threadIdx.x;
    if (i < n) {
        int v = off[i] + partials[blockIdx.x];
        off[i] = v;
        cursor[i] = v;
    }
    if (i == 0) off[n] = e_total;
}

// ---------------- scatter edges into CSR-by-dst ----------------
__global__ void scatter_kernel(const int* __restrict__ src, const int* __restrict__ dst,
                               int* __restrict__ cursor, int* __restrict__ ssorted, int e) {
    int i = blockIdx.x * blockDim.x + threadIdx.x;
    if (i < e) {
        int p = atomicAdd(&cursor[dst[i]], 1);
        ssorted[p] = src[i];
    }
}

// ---------------- propagation: one wave per node ----------------
__global__ __launch_bounds__(256) void prop_kernel(
        const float* __restrict__ xin, const int* __restrict__ ssorted,
        const int* __restrict__ off, const float* __restrict__ dinv,
        float* __restrict__ out, int n, int selfloop) {
    int wave = (blockIdx.x * blockDim.x + threadIdx.x) >> 6;
    int lane = threadIdx.x & 63;
    if (wave >= n) return;
    int e0 = off[wave], e1 = off[wave + 1];
    float ax = 0.0f, ay = 0.0f;
    for (int e = e0; e < e1; ++e) {
        int s = ssorted[e];
        float ds = dinv[s];
        float2 v = *(const float2*)&xin[(long)s * DP + lane * 2];
        ax += ds * v.x;
        ay += ds * v.y;
    }
    float dn = dinv[wave];
    float rx = dn * ax, ry = dn * ay;
    if (selfloop) {
        float2 v = *(const float2*)&xin[(long)wave * DP + lane * 2];
        float d2 = dn * dn;
        rx += d2 * v.x;
        ry += d2 * v.y;
    }
    float2 r; r.x = rx; r.y = ry;
    *(float2*)&out[(long)wave * DP + lane * 2] = r;
}

// ---------------- node-level matmul ----------------
__global__ __launch_bounds__(256) void matmul_kernel(
        const float* __restrict__ A, const float* __restrict__ W,
        const float* __restrict__ bias, const float* __restrict__ addend,
        float* __restrict__ C, int M, int K, int Kout, int relu) {
    extern __shared__ float Wl[];   // K * 128, Kout..127 zero-padded
    int tid = threadIdx.x;
    int total = K * DP;
    for (int idx = tid; idx < total; idx += 256) {
        int k = idx >> 7, c = idx & 127;
        Wl[idx] = (c < Kout) ? W[k * Kout + c] : 0.0f;
    }
    __syncthreads();

    int colg = tid & 31;       // 32 col-groups of 4
    int rowg = tid >> 5;       // 8 row-groups of 8
    long row0 = (long)blockIdx.x * 64 + rowg * 8;
    int c0 = colg * 4;

    float4 acc[8];
    long r[8];
#pragma unroll
    for (int i = 0; i < 8; i++) {
        acc[i] = make_float4(0.f, 0.f, 0.f, 0.f);
        long rr = row0 + i;
        r[i] = (rr < M) ? rr : (long)(M - 1);
    }

    for (int k = 0; k < K; k += 4) {
        float4 w0 = *(const float4*)&Wl[(k + 0) * DP + c0];
        float4 w1 = *(const float4*)&Wl[(k + 1) * DP + c0];
        float4 w2 = *(const float4*)&Wl[(k + 2) * DP + c0];
        float4 w3 = *(const float4*)&Wl[(k + 3) * DP + c0];
#pragma unroll
        for (int i = 0; i < 8; i++) {
            float4 a4 = *(const float4*)&A[r[i] * DP + k];
            acc[i].x += a4.x * w0.x + a4.y * w1.x + a4.z * w2.x + a4.w * w3.x;
            acc[i].y += a4.x * w0.y + a4.y * w1.y + a4.z * w2.y + a4.w * w3.y;
            acc[i].z += a4.x * w0.z + a4.y * w1.z + a4.z * w2.z + a4.w * w3.z;
            acc[i].w += a4.x * w0.w + a4.y * w1.w + a4.z * w2.w + a4.w * w3.w;
        }
    }

    float4 bv = make_float4(0.f, 0.f, 0.f, 0.f);
    if (bias && c0 < Kout) bv = *(const float4*)&bias[c0];

#pragma unroll
    for (int i = 0; i < 8; i++) {
        long rr = row0 + i;
        if (rr >= M) break;
        float4 v = acc[i];
        v.x += bv.x; v.y += bv.y; v.z += bv.z; v.w += bv.w;
        if (addend) {
            float4 ad = *(const float4*)&addend[rr * DP + c0];
            v.x += ad.x; v.y += ad.y; v.z += ad.z; v.w += ad.w;
        }
        if (relu) {
            v.x = fmaxf(v.x, 0.f); v.y = fmaxf(v.y, 0.f);
            v.z = fmaxf(v.z, 0.f); v.w = fmaxf(v.w, 0.f);
        }
        *(float4*)&C[rr * DP + c0] = v;
    }
}

// ---------------- batchnorm stats ----------------
__global__ void bn_stats_kernel(const float* __restrict__ h, float* __restrict__ sum,
                                float* __restrict__ sq, int n) {
    int col = threadIdx.x;   // 128 threads
    float s = 0.f, q = 0.f;
    for (int row = blockIdx.x; row < n; row += gridDim.x) {
        float v = h[(long)row * DP + col];
        s += v;
        q += v * v;
    }
    atomicAdd(&sum[col], s);
    atomicAdd(&sq[col], q);
}

__global__ void bn_apply_kernel(float* __restrict__ h, const float* __restrict__ sum,
                                const float* __restrict__ sq, const float* __restrict__ gamma,
                                const float* __restrict__ beta, int n) {
    long i = (long)blockIdx.x * blockDim.x + threadIdx.x;
    if (i >= (long)n * DP) return;
    int c = (int)(i & 127);
    if (c >= DIM) return;
    float inv_n = 1.0f / (float)n;
    float mu = sum[c] * inv_n;
    float var = sq[c] * inv_n - mu * mu;
    float rs = rsqrtf(var + EPSBN);
    h[i] = (h[i] - mu) * rs * gamma[c] + beta[c];
}

// ---------------- graph boundaries (batch is sorted) ----------------
__global__ void gbounds_kernel(const int* __restrict__ batch, int* __restrict__ gstart, int n) {
    int g = threadIdx.x;   // 512 threads, one per graph
    int lo = 0, hi = n;
    while (lo < hi) {
        int mid = (lo + hi) >> 1;
        if (batch[mid] < g) lo = mid + 1; else hi = mid;
    }
    gstart[g] = lo;        // first node with batch >= g
    if (g == 0) gstart[NGRAPH] = n;
}

// ---------------- global add pool: one block per graph, segmented reduce ----------------
__global__ __launch_bounds__(512) void pool_kernel(const float* __restrict__ a,
                                                   const int* __restrict__ gstart,
                                                   float* __restrict__ g) {
    __shared__ float red[512];
    int b = blockIdx.x, tid = threadIdx.x;
    int col = tid & 127;          // feature
    int quarter = tid >> 7;       // 4 row-strides
    int lo = gstart[b], hi = gstart[b + 1];
    float s = 0.f;
    for (int r = lo + quarter; r < hi; r += 4)
        s += a[(long)r * DP + col];
    red[tid] = s;
    __syncthreads();
    if (tid < 128)
        g[b * DP + tid] = red[tid] + red[tid + 128] + red[tid + 256] + red[tid + 384];
}

// ---------------- fused MLP head: one block per graph ----------------
__global__ __launch_bounds__(256) void mlp_kernel(
        const float* __restrict__ g,
        const float* __restrict__ Wf1, const float* __restrict__ bf1,
        const float* __restrict__ Wf2, const float* __restrict__ bf2,
        const float* __restrict__ Wf3, const float* __restrict__ bf3,
        const float* __restrict__ Wf4, const float* __restrict__ bf4,
        float* __restrict__ out) {
    __shared__ float a0[100], a1[200], a2[300], a3[200], red[256];
    int b = blockIdx.x, tid = threadIdx.x;
    if (tid < 100) a0[tid] = g[b * DP + tid];
    __syncthreads();
    for (int c = tid; c < 200; c += 256) {
        float s = bf1[c];
        for (int k = 0; k < 100; k++) s += a0[k] * Wf1[k * 200 + c];
        a1[c] = fmaxf(s, 0.f);
    }
    __syncthreads();
    for (int c = tid; c < 300; c += 256) {
        float s = bf2[c];
        for (int k = 0; k < 200; k++) s += a1[k] * Wf2[k * 300 + c];
        a2[c] = fmaxf(s, 0.f);
    }
    __syncthreads();
    for (int c = tid; c < 200; c += 256) {
        float s = bf3[c];
        for (int k = 0; k < 300; k++) s += a2[k] * Wf3[k * 200 + c];
        a3[c] = fmaxf(s, 0.f);
    }
    __syncthreads();
    red[tid] = (tid < 200) ? a3[tid] * Wf4[tid] : 0.f;
    __syncthreads();
    for (int o = 128; o > 0; o >>= 1) {
        if (tid < o) red[tid] += red[tid + o];
        __syncthreads();
    }
    if (tid == 0) out[b] = red[0] + bf4[0];
}

extern "C" void kernel_launch(void* const* d_in, const int* in_sizes, int n_in,
                              void* d_out, int out_size, void* d_ws, size_t ws_size,
                              hipStream_t stream) {
    const float* x      = (const float*)d_in[0];
    const int*   src    = (const int*)d_in[1];
    const int*   dst    = (const int*)d_in[2];
    const int*   batch  = (const int*)d_in[3];
    const float* W1     = (const float*)d_in[4];
    const float* b1     = (const float*)d_in[5];
    const float* W2     = (const float*)d_in[6];
    const float* b2     = (const float*)d_in[7];
    const float* gamma  = (const float*)d_in[8];
    const float* beta   = (const float*)d_in[9];
    const float* Wa_init= (const float*)d_in[10];
    const float* Wa_root= (const float*)d_in[11];
    const float* ba     = (const float*)d_in[12];
    const float* Wf1    = (const float*)d_in[13];
    const float* bf1    = (const float*)d_in[14];
    const float* Wf2    = (const float*)d_in[15];
    const float* bf2    = (const float*)d_in[16];
    const float* Wf3    = (const float*)d_in[17];
    const float* bf3    = (const float*)d_in[18];
    const float* Wf4    = (const float*)d_in[19];
    const float* bf4    = (const float*)d_in[20];
    float* out = (float*)d_out;

    const int n = NNODES;
    const int e = NEDGES;

    // ---- workspace carve (all 256B aligned) ----
    char* ws = (char*)d_ws;
    auto carve = [&](size_t bytes) -> void* {
        void* p = (void*)ws;
        ws += (bytes + 255) & ~(size_t)255;
        return p;
    };
    float* bufA    = (float*)carve((size_t)n * DP * 4);
    float* bufB    = (float*)carve((size_t)n * DP * 4);
    float* bufC    = (float*)carve((size_t)n * DP * 4);
    int*   hist    = (int*)carve((size_t)n * 4);
    int*   off     = (int*)carve((size_t)(n + 1) * 4);
    int*   cursor  = (int*)carve((size_t)n * 4);
    int*   partials= (int*)carve(512 * 4);
    int*   ssorted = (int*)carve((size_t)e * 4);
    float* dinv_sl = (float*)carve((size_t)n * 4);
    float* dinv_nsl= (float*)carve((size_t)n * 4);
    float* bnsum   = (float*)carve(DP * 4);
    float* bnsq    = (float*)carve(DP * 4);
    int*   gstart  = (int*)carve((size_t)(NGRAPH + 1) * 4);
    float* gpool   = (float*)carve((size_t)NGRAPH * DP * 4);

    const int nb = (n + 255) / 256;   // 391 scan blocks

    // ---- build CSR by dst ----
    hipMemsetAsync(hist, 0, (size_t)n * 4, stream);
    hist_kernel<<<(e + 255) / 256, 256, 0, stream>>>(dst, hist, e);
    dinv_kernel<<<(n + 255) / 256, 256, 0, stream>>>(hist, dinv_sl, dinv_nsl, n);
    scan1_kernel<<<nb, 256, 0, stream>>>(hist, off, partials, n);
    scan2_kernel<<<1, 512, 0, stream>>>(partials, nb);
    scan3_kernel<<<nb, 256, 0, stream>>>(off, partials, cursor, n, e);
    scatter_kernel<<<(e + 255) / 256, 256, 0, stream>>>(src, dst, cursor, ssorted, e);
    gbounds_kernel<<<1, 512, 0, stream>>>(batch, gstart, n);

    const int prop_blocks = (n + 3) / 4;   // 4 waves per 256-thread block

    // ---- SGConv 1: prop(x, self-loops) @ W1 + b1, relu ----
    prop_kernel<<<prop_blocks, 256, 0, stream>>>(x, ssorted, off, dinv_sl, bufA, n, 1);
    matmul_kernel<<<(n + 63) / 64, 256, 128 * DP * 4, stream>>>(bufA, W1, b1, nullptr, bufB, n, 128, DIM, 1);

    // ---- SGConv 2 ----
    prop_kernel<<<prop_blocks, 256, 0, stream>>>(bufB, ssorted, off, dinv_sl, bufA, n, 1);
    matmul_kernel<<<(n + 63) / 64, 256, DIM * DP * 4, stream>>>(bufA, W2, b2, nullptr, bufB, n, DIM, DIM, 1);

    // ---- BatchNorm (training stats) ----
    hipMemsetAsync(bnsum, 0, DP * 4, stream);
    hipMemsetAsync(bnsq, 0, DP * 4, stream);
    bn_stats_kernel<<<512, 128, 0, stream>>>(bufB, bnsum, bnsq, n);
    bn_apply_kernel<<<(int)(((long)n * DP + 255) / 256), 256, 0, stream>>>(bufB, bnsum, bnsq, gamma, beta, n);

    // ---- ARMAConv: relu(prop(h @ Wa_init, no self-loops) + h @ Wa_root + ba) ----
    matmul_kernel<<<(n + 63) / 64, 256, DIM * DP * 4, stream>>>(bufB, Wa_init, nullptr, nullptr, bufA, n, DIM, DIM, 0);
    prop_kernel<<<prop_blocks, 256, 0, stream>>>(bufA, ssorted, off, dinv_nsl, bufC, n, 0);
    matmul_kernel<<<(n + 63) / 64, 256, DIM * DP * 4, stream>>>(bufB, Wa_root, ba, bufC, bufA, n, DIM, DIM, 1);

    // ---- global add pool (segmented reduce over sorted batch) ----
    pool_kernel<<<NGRAPH, 512, 0, stream>>>(bufA, gstart, gpool);

    // ---- MLP head ----
    mlp_kernel<<<NGRAPH, 256, 0, stream>>>(gpool, Wf1, bf1, Wf2, bf2, Wf3, bf3, Wf4, bf4, out);
}

// Round 3
// 1395.570 us; speedup vs baseline: 1.2032x; 1.0924x over previous
//
#include <hip/hip_runtime.h>

#define NNODES 100000
#define NEDGES 1600000
#define NGRAPH 512
#define DIM    100
#define DP     128
#define EPSBN  1e-5f

// ---------------- degree histogram ----------------
__global__ void hist_kernel(const int* __restrict__ dst, int* __restrict__ hist, int e) {
    int i = blockIdx.x * blockDim.x + threadIdx.x;
    if (i < e) atomicAdd(&hist[dst[i]], 1);
}

// ---------------- dinv (with and without self loops) ----------------
__global__ void dinv_kernel(const int* __restrict__ hist, float* __restrict__ dsl,
                            float* __restrict__ dnsl, int n) {
    int i = blockIdx.x * blockDim.x + threadIdx.x;
    if (i >= n) return;
    float c = (float)hist[i];
    dsl[i]  = rsqrtf(c + 1.0f);
    dnsl[i] = (c > 0.0f) ? rsqrtf(c) : 0.0f;
}

// ---------------- two-level exclusive scan over hist (256/block) ----------------
__global__ void scan1_kernel(const int* __restrict__ hist, int* __restrict__ off,
                             int* __restrict__ partials, int n) {
    __shared__ int s[256];
    int i = blockIdx.x * 256 + threadIdx.x;
    int v = (i < n) ? hist[i] : 0;
    s[threadIdx.x] = v; __syncthreads();
    for (int o = 1; o < 256; o <<= 1) {
        int t = (threadIdx.x >= o) ? s[threadIdx.x - o] : 0;
        __syncthreads();
        s[threadIdx.x] += t;
        __syncthreads();
    }
    if (i < n) off[i] = s[threadIdx.x] - v;
    if (threadIdx.x == 255) partials[blockIdx.x] = s[255];
}

__global__ void scan2_kernel(int* __restrict__ partials, int nb) {
    __shared__ int s[512];
    int v = (threadIdx.x < nb) ? partials[threadIdx.x] : 0;
    s[threadIdx.x] = v; __syncthreads();
    for (int o = 1; o < 512; o <<= 1) {
        int t = (threadIdx.x >= o) ? s[threadIdx.x - o] : 0;
        __syncthreads();
        s[threadIdx.x] += t;
        __syncthreads();
    }
    if (threadIdx.x < nb) partials[threadIdx.x] = s[threadIdx.x] - v;
}

__global__ void scan3_kernel(int* __restrict__ off, const int* __restrict__ partials,
                             int* __restrict__ cursor, int n, int e_total) {
    int i = blockIdx.x * 256 + threadIdx.x;
    if (i < n) {
        int v = off[i] + partials[blockIdx.x];
        off[i] = v;
        cursor[i] = v;
    }
    if (i == 0) off[n] = e_total;
}

// ---------------- scatter edges into CSR-by-dst ----------------
__global__ void scatter_kernel(const int* __restrict__ src, const int* __restrict__ dst,
                               int* __restrict__ cursor, int* __restrict__ ssorted, int e) {
    int i = blockIdx.x * blockDim.x + threadIdx.x;
    if (i < e) {
        int p = atomicAdd(&cursor[dst[i]], 1);
        ssorted[p] = src[i];
    }
}

// ---------------- prescale rows: y[i,:] = x[i,:] * d[i] ----------------
__global__ void prescale_kernel(const float* __restrict__ x, const float* __restrict__ d,
                                float* __restrict__ y, int n) {
    long i = (long)blockIdx.x * blockDim.x + threadIdx.x;   // one float4 per thread
    if (i >= (long)n * 32) return;
    int row = (int)(i >> 5);
    float s = d[row];
    float4 v = ((const float4*)x)[i];
    v.x *= s; v.y *= s; v.z *= s; v.w *= s;
    ((float4*)y)[i] = v;
}

// ---------------- propagation: one wave per node, prescaled input ----------------
// out[n,:] = dinv[n] * ( sum_e pre[src_e,:]  (+ selfloop: pre[n,:]) )
__global__ __launch_bounds__(256) void prop_kernel(
        const float* __restrict__ pre, const int* __restrict__ ssorted,
        const int* __restrict__ off, const float* __restrict__ dinv,
        float* __restrict__ out, int n, int selfloop) {
    int wave = (blockIdx.x * blockDim.x + threadIdx.x) >> 6;
    int lane = threadIdx.x & 63;
    if (wave >= n) return;
    int e0 = off[wave], e1 = off[wave + 1];
    int deg = e1 - e0;
    int half = lane >> 5;       // 0/1: which edge of the pair
    int l32  = lane & 31;
    int c0 = l32 * 4;           // 32 lanes x float4 = 128 cols

    float4 acc = make_float4(0.f, 0.f, 0.f, 0.f);

    for (int base = 0; base < deg; base += 64) {
        int m = deg - base; if (m > 64) m = 64;
        int sidx = (lane < m) ? ssorted[e0 + base + lane] : 0;
        int j = 0;
        // 4 edges in flight per wave per iteration
        for (; j + 4 <= m; j += 4) {
            int sA = __shfl(sidx, j + half);
            int sB = __shfl(sidx, j + 2 + half);
            float4 vA = *(const float4*)&pre[(long)sA * DP + c0];
            float4 vB = *(const float4*)&pre[(long)sB * DP + c0];
            acc.x += vA.x + vB.x; acc.y += vA.y + vB.y;
            acc.z += vA.z + vB.z; acc.w += vA.w + vB.w;
        }
        for (; j + 2 <= m; j += 2) {
            int s = __shfl(sidx, j + half);
            float4 v = *(const float4*)&pre[(long)s * DP + c0];
            acc.x += v.x; acc.y += v.y; acc.z += v.z; acc.w += v.w;
        }
        if (j < m) {            // odd tail: only half 0 contributes
            int s = __shfl(sidx, j);
            if (half == 0) {
                float4 v = *(const float4*)&pre[(long)s * DP + c0];
                acc.x += v.x; acc.y += v.y; acc.z += v.z; acc.w += v.w;
            }
        }
    }

    // combine halves: every lane pulls from its upper-half partner
    acc.x += __shfl(acc.x, l32 + 32);
    acc.y += __shfl(acc.y, l32 + 32);
    acc.z += __shfl(acc.z, l32 + 32);
    acc.w += __shfl(acc.w, l32 + 32);

    if (half == 0) {
        float dn = dinv[wave];
        if (selfloop) {
            float4 sv = *(const float4*)&pre[(long)wave * DP + c0];
            acc.x += sv.x; acc.y += sv.y; acc.z += sv.z; acc.w += sv.w;
        }
        float4 r;
        r.x = dn * acc.x; r.y = dn * acc.y; r.z = dn * acc.z; r.w = dn * acc.w;
        *(float4*)&out[(long)wave * DP + c0] = r;
    }
}

// ---------------- node-level matmul (+optional per-row output scale) ----------------
__global__ __launch_bounds__(256) void matmul_kernel(
        const float* __restrict__ A, const float* __restrict__ W,
        const float* __restrict__ bias, const float* __restrict__ addend,
        const float* __restrict__ rowscale,
        float* __restrict__ C, int M, int K, int Kout, int relu) {
    extern __shared__ float Wl[];   // K * 128, Kout..127 zero-padded
    int tid = threadIdx.x;
    int total = K * DP;
    for (int idx = tid; idx < total; idx += 256) {
        int k = idx >> 7, c = idx & 127;
        Wl[idx] = (c < Kout) ? W[k * Kout + c] : 0.0f;
    }
    __syncthreads();

    int colg = tid & 31;
    int rowg = tid >> 5;
    long row0 = (long)blockIdx.x * 64 + rowg * 8;
    int c0 = colg * 4;

    float4 acc[8];
    long r[8];
#pragma unroll
    for (int i = 0; i < 8; i++) {
        acc[i] = make_float4(0.f, 0.f, 0.f, 0.f);
        long rr = row0 + i;
        r[i] = (rr < M) ? rr : (long)(M - 1);
    }

    for (int k = 0; k < K; k += 4) {
        float4 w0 = *(const float4*)&Wl[(k + 0) * DP + c0];
        float4 w1 = *(const float4*)&Wl[(k + 1) * DP + c0];
        float4 w2 = *(const float4*)&Wl[(k + 2) * DP + c0];
        float4 w3 = *(const float4*)&Wl[(k + 3) * DP + c0];
#pragma unroll
        for (int i = 0; i < 8; i++) {
            float4 a4 = *(const float4*)&A[r[i] * DP + k];
            acc[i].x += a4.x * w0.x + a4.y * w1.x + a4.z * w2.x + a4.w * w3.x;
            acc[i].y += a4.x * w0.y + a4.y * w1.y + a4.z * w2.y + a4.w * w3.y;
            acc[i].z += a4.x * w0.z + a4.y * w1.z + a4.z * w2.z + a4.w * w3.z;
            acc[i].w += a4.x * w0.w + a4.y * w1.w + a4.z * w2.w + a4.w * w3.w;
        }
    }

    float4 bv = make_float4(0.f, 0.f, 0.f, 0.f);
    if (bias && c0 < Kout) bv = *(const float4*)&bias[c0];

#pragma unroll
    for (int i = 0; i < 8; i++) {
        long rr = row0 + i;
        if (rr >= M) break;
        float4 v = acc[i];
        v.x += bv.x; v.y += bv.y; v.z += bv.z; v.w += bv.w;
        if (addend) {
            float4 ad = *(const float4*)&addend[rr * DP + c0];
            v.x += ad.x; v.y += ad.y; v.z += ad.z; v.w += ad.w;
        }
        if (relu) {
            v.x = fmaxf(v.x, 0.f); v.y = fmaxf(v.y, 0.f);
            v.z = fmaxf(v.z, 0.f); v.w = fmaxf(v.w, 0.f);
        }
        if (rowscale) {
            float rs = rowscale[rr];
            v.x *= rs; v.y *= rs; v.z *= rs; v.w *= rs;
        }
        *(float4*)&C[rr * DP + c0] = v;
    }
}

// ---------------- batchnorm stats ----------------
__global__ void bn_stats_kernel(const float* __restrict__ h, float* __restrict__ sum,
                                float* __restrict__ sq, int n) {
    int col = threadIdx.x;   // 128 threads
    float s = 0.f, q = 0.f;
    for (int row = blockIdx.x; row < n; row += gridDim.x) {
        float v = h[(long)row * DP + col];
        s += v;
        q += v * v;
    }
    atomicAdd(&sum[col], s);
    atomicAdd(&sq[col], q);
}

__global__ void bn_apply_kernel(float* __restrict__ h, const float* __restrict__ sum,
                                const float* __restrict__ sq, const float* __restrict__ gamma,
                                const float* __restrict__ beta, int n) {
    long i = (long)blockIdx.x * blockDim.x + threadIdx.x;
    if (i >= (long)n * DP) return;
    int c = (int)(i & 127);
    if (c >= DIM) return;
    float inv_n = 1.0f / (float)n;
    float mu = sum[c] * inv_n;
    float var = sq[c] * inv_n - mu * mu;
    float rs = rsqrtf(var + EPSBN);
    h[i] = (h[i] - mu) * rs * gamma[c] + beta[c];
}

// ---------------- graph boundaries (batch is sorted) ----------------
__global__ void gbounds_kernel(const int* __restrict__ batch, int* __restrict__ gstart, int n) {
    int g = threadIdx.x;
    int lo = 0, hi = n;
    while (lo < hi) {
        int mid = (lo + hi) >> 1;
        if (batch[mid] < g) lo = mid + 1; else hi = mid;
    }
    gstart[g] = lo;
    if (g == 0) gstart[NGRAPH] = n;
}

// ---------------- global add pool: one block per graph, segmented reduce ----------------
__global__ __launch_bounds__(512) void pool_kernel(const float* __restrict__ a,
                                                   const int* __restrict__ gstart,
                                                   float* __restrict__ g) {
    __shared__ float red[512];
    int b = blockIdx.x, tid = threadIdx.x;
    int col = tid & 127;
    int quarter = tid >> 7;
    int lo = gstart[b], hi = gstart[b + 1];
    float s = 0.f;
    for (int r = lo + quarter; r < hi; r += 4)
        s += a[(long)r * DP + col];
    red[tid] = s;
    __syncthreads();
    if (tid < 128)
        g[b * DP + tid] = red[tid] + red[tid + 128] + red[tid + 256] + red[tid + 384];
}

// ---------------- fused MLP head: one block per graph ----------------
__global__ __launch_bounds__(256) void mlp_kernel(
        const float* __restrict__ g,
        const float* __restrict__ Wf1, const float* __restrict__ bf1,
        const float* __restrict__ Wf2, const float* __restrict__ bf2,
        const float* __restrict__ Wf3, const float* __restrict__ bf3,
        const float* __restrict__ Wf4, const float* __restrict__ bf4,
        float* __restrict__ out) {
    __shared__ float a0[100], a1[200], a2[300], a3[200], red[256];
    int b = blockIdx.x, tid = threadIdx.x;
    if (tid < 100) a0[tid] = g[b * DP + tid];
    __syncthreads();
    for (int c = tid; c < 200; c += 256) {
        float s = bf1[c];
        for (int k = 0; k < 100; k++) s += a0[k] * Wf1[k * 200 + c];
        a1[c] = fmaxf(s, 0.f);
    }
    __syncthreads();
    for (int c = tid; c < 300; c += 256) {
        float s = bf2[c];
        for (int k = 0; k < 200; k++) s += a1[k] * Wf2[k * 300 + c];
        a2[c] = fmaxf(s, 0.f);
    }
    __syncthreads();
    for (int c = tid; c < 200; c += 256) {
        float s = bf3[c];
        for (int k = 0; k < 300; k++) s += a2[k] * Wf3[k * 200 + c];
        a3[c] = fmaxf(s, 0.f);
    }
    __syncthreads();
    red[tid] = (tid < 200) ? a3[tid] * Wf4[tid] : 0.f;
    __syncthreads();
    for (int o = 128; o > 0; o >>= 1) {
        if (tid < o) red[tid] += red[tid + o];
        __syncthreads();
    }
    if (tid == 0) out[b] = red[0] + bf4[0];
}

extern "C" void kernel_launch(void* const* d_in, const int* in_sizes, int n_in,
                              void* d_out, int out_size, void* d_ws, size_t ws_size,
                              hipStream_t stream) {
    const float* x      = (const float*)d_in[0];
    const int*   src    = (const int*)d_in[1];
    const int*   dst    = (const int*)d_in[2];
    const int*   batch  = (const int*)d_in[3];
    const float* W1     = (const float*)d_in[4];
    const float* b1     = (const float*)d_in[5];
    const float* W2     = (const float*)d_in[6];
    const float* b2     = (const float*)d_in[7];
    const float* gamma  = (const float*)d_in[8];
    const float* beta   = (const float*)d_in[9];
    const float* Wa_init= (const float*)d_in[10];
    const float* Wa_root= (const float*)d_in[11];
    const float* ba     = (const float*)d_in[12];
    const float* Wf1    = (const float*)d_in[13];
    const float* bf1    = (const float*)d_in[14];
    const float* Wf2    = (const float*)d_in[15];
    const float* bf2    = (const float*)d_in[16];
    const float* Wf3    = (const float*)d_in[17];
    const float* bf3    = (const float*)d_in[18];
    const float* Wf4    = (const float*)d_in[19];
    const float* bf4    = (const float*)d_in[20];
    float* out = (float*)d_out;

    const int n = NNODES;
    const int e = NEDGES;

    char* ws = (char*)d_ws;
    auto carve = [&](size_t bytes) -> void* {
        void* p = (void*)ws;
        ws += (bytes + 255) & ~(size_t)255;
        return p;
    };
    float* bufA    = (float*)carve((size_t)n * DP * 4);
    float* bufB    = (float*)carve((size_t)n * DP * 4);
    float* bufC    = (float*)carve((size_t)n * DP * 4);
    int*   hist    = (int*)carve((size_t)n * 4);
    int*   off     = (int*)carve((size_t)(n + 1) * 4);
    int*   cursor  = (int*)carve((size_t)n * 4);
    int*   partials= (int*)carve(512 * 4);
    int*   ssorted = (int*)carve((size_t)e * 4);
    float* dinv_sl = (float*)carve((size_t)n * 4);
    float* dinv_nsl= (float*)carve((size_t)n * 4);
    float* bnsum   = (float*)carve(DP * 4);
    float* bnsq    = (float*)carve(DP * 4);
    int*   gstart  = (int*)carve((size_t)(NGRAPH + 1) * 4);
    float* gpool   = (float*)carve((size_t)NGRAPH * DP * 4);

    const int nb = (n + 255) / 256;

    // ---- build CSR by dst ----
    hipMemsetAsync(hist, 0, (size_t)n * 4, stream);
    hist_kernel<<<(e + 255) / 256, 256, 0, stream>>>(dst, hist, e);
    dinv_kernel<<<(n + 255) / 256, 256, 0, stream>>>(hist, dinv_sl, dinv_nsl, n);
    scan1_kernel<<<nb, 256, 0, stream>>>(hist, off, partials, n);
    scan2_kernel<<<1, 512, 0, stream>>>(partials, nb);
    scan3_kernel<<<nb, 256, 0, stream>>>(off, partials, cursor, n, e);
    scatter_kernel<<<(e + 255) / 256, 256, 0, stream>>>(src, dst, cursor, ssorted, e);
    gbounds_kernel<<<1, 512, 0, stream>>>(batch, gstart, n);

    const int prop_blocks = (n + 3) / 4;
    const int mm_blocks = (n + 63) / 64;

    // ---- SGConv 1: pre = x*dinv_sl; prop; @W1+b1 relu, output pre-scaled by dinv_sl ----
    prescale_kernel<<<(int)(((long)n * 32 + 255) / 256), 256, 0, stream>>>(x, dinv_sl, bufC, n);
    prop_kernel<<<prop_blocks, 256, 0, stream>>>(bufC, ssorted, off, dinv_sl, bufA, n, 1);
    matmul_kernel<<<mm_blocks, 256, 128 * DP * 4, stream>>>(bufA, W1, b1, nullptr, dinv_sl, bufB, n, 128, DIM, 1);

    // ---- SGConv 2: prop on pre-scaled h1; @W2+b2 relu (unscaled — BN needs h2) ----
    prop_kernel<<<prop_blocks, 256, 0, stream>>>(bufB, ssorted, off, dinv_sl, bufA, n, 1);
    matmul_kernel<<<mm_blocks, 256, DIM * DP * 4, stream>>>(bufA, W2, b2, nullptr, nullptr, bufB, n, DIM, DIM, 1);

    // ---- BatchNorm (training stats) ----
    hipMemsetAsync(bnsum, 0, DP * 4, stream);
    hipMemsetAsync(bnsq, 0, DP * 4, stream);
    bn_stats_kernel<<<512, 128, 0, stream>>>(bufB, bnsum, bnsq, n);
    bn_apply_kernel<<<(int)(((long)n * DP + 255) / 256), 256, 0, stream>>>(bufB, bnsum, bnsq, gamma, beta, n);

    // ---- ARMAConv: t = (h@Wa_init)*dinv_nsl ; prop(no SL) ; relu(h@Wa_root + ba + t_prop) ----
    matmul_kernel<<<mm_blocks, 256, DIM * DP * 4, stream>>>(bufB, Wa_init, nullptr, nullptr, dinv_nsl, bufA, n, DIM, DIM, 0);
    prop_kernel<<<prop_blocks, 256, 0, stream>>>(bufA, ssorted, off, dinv_nsl, bufC, n, 0);
    matmul_kernel<<<mm_blocks, 256, DIM * DP * 4, stream>>>(bufB, Wa_root, ba, bufC, nullptr, bufA, n, DIM, DIM, 1);

    // ---- global add pool (segmented reduce over sorted batch) ----
    pool_kernel<<<NGRAPH, 512, 0, stream>>>(bufA, gstart, gpool);

    // ---- MLP head ----
    mlp_kernel<<<NGRAPH, 256, 0, stream>>>(gpool, Wf1, bf1, Wf2, bf2, Wf3, bf3, Wf4, bf4, out);
}

// Round 4
// 1065.504 us; speedup vs baseline: 1.5760x; 1.3098x over previous
//
#include <hip/hip_runtime.h>

#define NNODES 100000
#define NEDGES 1600000
#define NGRAPH 512
#define DIM    100
#define DP     128
#define EPSBN  1e-5f

// ---------------- degree histogram ----------------
__global__ void hist_kernel(const int* __restrict__ dst, int* __restrict__ hist, int e) {
    int i = blockIdx.x * blockDim.x + threadIdx.x;
    if (i < e) atomicAdd(&hist[dst[i]], 1);
}

// ---------------- dinv (with and without self loops) ----------------
__global__ void dinv_kernel(const int* __restrict__ hist, float* __restrict__ dsl,
                            float* __restrict__ dnsl, int n) {
    int i = blockIdx.x * blockDim.x + threadIdx.x;
    if (i >= n) return;
    float c = (float)hist[i];
    dsl[i]  = rsqrtf(c + 1.0f);
    dnsl[i] = (c > 0.0f) ? rsqrtf(c) : 0.0f;
}

// ---------------- two-level exclusive scan over hist (256/block) ----------------
__global__ void scan1_kernel(const int* __restrict__ hist, int* __restrict__ off,
                             int* __restrict__ partials, int n) {
    __shared__ int s[256];
    int i = blockIdx.x * 256 + threadIdx.x;
    int v = (i < n) ? hist[i] : 0;
    s[threadIdx.x] = v; __syncthreads();
    for (int o = 1; o < 256; o <<= 1) {
        int t = (threadIdx.x >= o) ? s[threadIdx.x - o] : 0;
        __syncthreads();
        s[threadIdx.x] += t;
        __syncthreads();
    }
    if (i < n) off[i] = s[threadIdx.x] - v;
    if (threadIdx.x == 255) partials[blockIdx.x] = s[255];
}

__global__ void scan2_kernel(int* __restrict__ partials, int nb) {
    __shared__ int s[512];
    int v = (threadIdx.x < nb) ? partials[threadIdx.x] : 0;
    s[threadIdx.x] = v; __syncthreads();
    for (int o = 1; o < 512; o <<= 1) {
        int t = (threadIdx.x >= o) ? s[threadIdx.x - o] : 0;
        __syncthreads();
        s[threadIdx.x] += t;
        __syncthreads();
    }
    if (threadIdx.x < nb) partials[threadIdx.x] = s[threadIdx.x] - v;
}

__global__ void scan3_kernel(int* __restrict__ off, const int* __restrict__ partials,
                             int* __restrict__ cursor, int n, int e_total) {
    int i = blockIdx.x * 256 + threadIdx.x;
    if (i < n) {
        int v = off[i] + partials[blockIdx.x];
        off[i] = v;
        cursor[i] = v;
    }
    if (i == 0) off[n] = e_total;
}

// ---------------- scatter edges into CSR-by-dst ----------------
__global__ void scatter_kernel(const int* __restrict__ src, const int* __restrict__ dst,
                               int* __restrict__ cursor, int* __restrict__ ssorted, int e) {
    int i = blockIdx.x * blockDim.x + threadIdx.x;
    if (i < e) {
        int p = atomicAdd(&cursor[dst[i]], 1);
        ssorted[p] = src[i];
    }
}

// ---------------- prescale rows: y[i,:] = x[i,:] * d[i] ----------------
__global__ void prescale_kernel(const float* __restrict__ x, const float* __restrict__ d,
                                float* __restrict__ y, int n) {
    long i = (long)blockIdx.x * blockDim.x + threadIdx.x;
    if (i >= (long)n * 32) return;
    int row = (int)(i >> 5);
    float s = d[row];
    float4 v = ((const float4*)x)[i];
    v.x *= s; v.y *= s; v.z *= s; v.w *= s;
    ((float4*)y)[i] = v;
}

// ---------------- propagation: one wave per node, prescaled input ----------------
__global__ __launch_bounds__(256) void prop_kernel(
        const float* __restrict__ pre, const int* __restrict__ ssorted,
        const int* __restrict__ off, const float* __restrict__ dinv,
        float* __restrict__ out, int n, int selfloop) {
    int wave = (blockIdx.x * blockDim.x + threadIdx.x) >> 6;
    int lane = threadIdx.x & 63;
    if (wave >= n) return;
    int e0 = off[wave], e1 = off[wave + 1];
    int deg = e1 - e0;
    int half = lane >> 5;
    int l32  = lane & 31;
    int c0 = l32 * 4;

    float4 acc = make_float4(0.f, 0.f, 0.f, 0.f);

    for (int base = 0; base < deg; base += 64) {
        int m = deg - base; if (m > 64) m = 64;
        int sidx = (lane < m) ? ssorted[e0 + base + lane] : 0;
        int j = 0;
        for (; j + 4 <= m; j += 4) {
            int sA = __shfl(sidx, j + half);
            int sB = __shfl(sidx, j + 2 + half);
            float4 vA = *(const float4*)&pre[(long)sA * DP + c0];
            float4 vB = *(const float4*)&pre[(long)sB * DP + c0];
            acc.x += vA.x + vB.x; acc.y += vA.y + vB.y;
            acc.z += vA.z + vB.z; acc.w += vA.w + vB.w;
        }
        for (; j + 2 <= m; j += 2) {
            int s = __shfl(sidx, j + half);
            float4 v = *(const float4*)&pre[(long)s * DP + c0];
            acc.x += v.x; acc.y += v.y; acc.z += v.z; acc.w += v.w;
        }
        if (j < m) {
            int s = __shfl(sidx, j);
            if (half == 0) {
                float4 v = *(const float4*)&pre[(long)s * DP + c0];
                acc.x += v.x; acc.y += v.y; acc.z += v.z; acc.w += v.w;
            }
        }
    }

    acc.x += __shfl(acc.x, l32 + 32);
    acc.y += __shfl(acc.y, l32 + 32);
    acc.z += __shfl(acc.z, l32 + 32);
    acc.w += __shfl(acc.w, l32 + 32);

    if (half == 0) {
        float dn = dinv[wave];
        if (selfloop) {
            float4 sv = *(const float4*)&pre[(long)wave * DP + c0];
            acc.x += sv.x; acc.y += sv.y; acc.z += sv.z; acc.w += sv.w;
        }
        float4 r;
        r.x = dn * acc.x; r.y = dn * acc.y; r.z = dn * acc.z; r.w = dn * acc.w;
        *(float4*)&out[(long)wave * DP + c0] = r;
    }
}

// ---------------- node-level matmul: A-tile in LDS (32 KB), W from L2 ----------------
__global__ __launch_bounds__(256) void matmul_kernel(
        const float* __restrict__ A, const float* __restrict__ W,
        const float* __restrict__ bias, const float* __restrict__ addend,
        const float* __restrict__ rowscale,
        float* __restrict__ C, int M, int K, int Kout, int relu) {
    __shared__ float Al[64 * DP];       // 64 rows x 128 cols = 32 KB
    int tid = threadIdx.x;
    long row0blk = (long)blockIdx.x * 64;

    // cooperative coalesced A-tile load: 2048 float4, 8 per thread
    {
        const float4* Ag = (const float4*)A;
        float4* As = (float4*)Al;
        for (int j = tid; j < 64 * 32; j += 256) {
            long gr = row0blk + (j >> 5);
            if (gr >= M) gr = M - 1;
            As[j] = Ag[gr * 32 + (j & 31)];
        }
    }
    __syncthreads();

    int colg = tid & 31;
    int rowg = tid >> 5;
    int c0 = colg * 4;
    bool cvalid = (c0 < Kout);          // W pad guard (Kout..127 behave as zero)
    long row0 = row0blk + rowg * 8;

    float4 acc[8];
#pragma unroll
    for (int i = 0; i < 8; i++) acc[i] = make_float4(0.f, 0.f, 0.f, 0.f);

    const float4 z4 = make_float4(0.f, 0.f, 0.f, 0.f);
#pragma unroll 2
    for (int k = 0; k < K; k += 4) {
        float4 w0 = cvalid ? *(const float4*)&W[(k + 0) * Kout + c0] : z4;
        float4 w1 = cvalid ? *(const float4*)&W[(k + 1) * Kout + c0] : z4;
        float4 w2 = cvalid ? *(const float4*)&W[(k + 2) * Kout + c0] : z4;
        float4 w3 = cvalid ? *(const float4*)&W[(k + 3) * Kout + c0] : z4;
#pragma unroll
        for (int i = 0; i < 8; i++) {
            float4 a4 = *(const float4*)&Al[(rowg * 8 + i) * DP + k];
            acc[i].x += a4.x * w0.x + a4.y * w1.x + a4.z * w2.x + a4.w * w3.x;
            acc[i].y += a4.x * w0.y + a4.y * w1.y + a4.z * w2.y + a4.w * w3.y;
            acc[i].z += a4.x * w0.z + a4.y * w1.z + a4.z * w2.z + a4.w * w3.z;
            acc[i].w += a4.x * w0.w + a4.y * w1.w + a4.z * w2.w + a4.w * w3.w;
        }
    }

    float4 bv = make_float4(0.f, 0.f, 0.f, 0.f);
    if (bias && cvalid) bv = *(const float4*)&bias[c0];

#pragma unroll
    for (int i = 0; i < 8; i++) {
        long rr = row0 + i;
        if (rr >= M) break;
        float4 v = acc[i];
        v.x += bv.x; v.y += bv.y; v.z += bv.z; v.w += bv.w;
        if (addend) {
            float4 ad = *(const float4*)&addend[rr * DP + c0];
            v.x += ad.x; v.y += ad.y; v.z += ad.z; v.w += ad.w;
        }
        if (relu) {
            v.x = fmaxf(v.x, 0.f); v.y = fmaxf(v.y, 0.f);
            v.z = fmaxf(v.z, 0.f); v.w = fmaxf(v.w, 0.f);
        }
        if (rowscale) {
            float rs = rowscale[rr];
            v.x *= rs; v.y *= rs; v.z *= rs; v.w *= rs;
        }
        *(float4*)&C[rr * DP + c0] = v;
    }
}

// ---------------- batchnorm stats ----------------
__global__ void bn_stats_kernel(const float* __restrict__ h, float* __restrict__ sum,
                                float* __restrict__ sq, int n) {
    int col = threadIdx.x;
    float s = 0.f, q = 0.f;
    for (int row = blockIdx.x; row < n; row += gridDim.x) {
        float v = h[(long)row * DP + col];
        s += v;
        q += v * v;
    }
    atomicAdd(&sum[col], s);
    atomicAdd(&sq[col], q);
}

__global__ void bn_apply_kernel(float* __restrict__ h, const float* __restrict__ sum,
                                const float* __restrict__ sq, const float* __restrict__ gamma,
                                const float* __restrict__ beta, int n) {
    long i = (long)blockIdx.x * blockDim.x + threadIdx.x;
    if (i >= (long)n * DP) return;
    int c = (int)(i & 127);
    if (c >= DIM) return;
    float inv_n = 1.0f / (float)n;
    float mu = sum[c] * inv_n;
    float var = sq[c] * inv_n - mu * mu;
    float rs = rsqrtf(var + EPSBN);
    h[i] = (h[i] - mu) * rs * gamma[c] + beta[c];
}

// ---------------- graph boundaries (batch is sorted) ----------------
__global__ void gbounds_kernel(const int* __restrict__ batch, int* __restrict__ gstart, int n) {
    int g = threadIdx.x;
    int lo = 0, hi = n;
    while (lo < hi) {
        int mid = (lo + hi) >> 1;
        if (batch[mid] < g) lo = mid + 1; else hi = mid;
    }
    gstart[g] = lo;
    if (g == 0) gstart[NGRAPH] = n;
}

// ---------------- global add pool ----------------
__global__ __launch_bounds__(512) void pool_kernel(const float* __restrict__ a,
                                                   const int* __restrict__ gstart,
                                                   float* __restrict__ g) {
    __shared__ float red[512];
    int b = blockIdx.x, tid = threadIdx.x;
    int col = tid & 127;
    int quarter = tid >> 7;
    int lo = gstart[b], hi = gstart[b + 1];
    float s = 0.f;
    for (int r = lo + quarter; r < hi; r += 4)
        s += a[(long)r * DP + col];
    red[tid] = s;
    __syncthreads();
    if (tid < 128)
        g[b * DP + tid] = red[tid] + red[tid + 128] + red[tid + 256] + red[tid + 384];
}

// ---------------- fused MLP head ----------------
__global__ __launch_bounds__(256) void mlp_kernel(
        const float* __restrict__ g,
        const float* __restrict__ Wf1, const float* __restrict__ bf1,
        const float* __restrict__ Wf2, const float* __restrict__ bf2,
        const float* __restrict__ Wf3, const float* __restrict__ bf3,
        const float* __restrict__ Wf4, const float* __restrict__ bf4,
        float* __restrict__ out) {
    __shared__ float a0[100], a1[200], a2[300], a3[200], red[256];
    int b = blockIdx.x, tid = threadIdx.x;
    if (tid < 100) a0[tid] = g[b * DP + tid];
    __syncthreads();
    for (int c = tid; c < 200; c += 256) {
        float s = bf1[c];
        for (int k = 0; k < 100; k++) s += a0[k] * Wf1[k * 200 + c];
        a1[c] = fmaxf(s, 0.f);
    }
    __syncthreads();
    for (int c = tid; c < 300; c += 256) {
        float s = bf2[c];
        for (int k = 0; k < 200; k++) s += a1[k] * Wf2[k * 300 + c];
        a2[c] = fmaxf(s, 0.f);
    }
    __syncthreads();
    for (int c = tid; c < 200; c += 256) {
        float s = bf3[c];
        for (int k = 0; k < 300; k++) s += a2[k] * Wf3[k * 200 + c];
        a3[c] = fmaxf(s, 0.f);
    }
    __syncthreads();
    red[tid] = (tid < 200) ? a3[tid] * Wf4[tid] : 0.f;
    __syncthreads();
    for (int o = 128; o > 0; o >>= 1) {
        if (tid < o) red[tid] += red[tid + o];
        __syncthreads();
    }
    if (tid == 0) out[b] = red[0] + bf4[0];
}

extern "C" void kernel_launch(void* const* d_in, const int* in_sizes, int n_in,
                              void* d_out, int out_size, void* d_ws, size_t ws_size,
                              hipStream_t stream) {
    const float* x      = (const float*)d_in[0];
    const int*   src    = (const int*)d_in[1];
    const int*   dst    = (const int*)d_in[2];
    const int*   batch  = (const int*)d_in[3];
    const float* W1     = (const float*)d_in[4];
    const float* b1     = (const float*)d_in[5];
    const float* W2     = (const float*)d_in[6];
    const float* b2     = (const float*)d_in[7];
    const float* gamma  = (const float*)d_in[8];
    const float* beta   = (const float*)d_in[9];
    const float* Wa_init= (const float*)d_in[10];
    const float* Wa_root= (const float*)d_in[11];
    const float* ba     = (const float*)d_in[12];
    const float* Wf1    = (const float*)d_in[13];
    const float* bf1    = (const float*)d_in[14];
    const float* Wf2    = (const float*)d_in[15];
    const float* bf2    = (const float*)d_in[16];
    const float* Wf3    = (const float*)d_in[17];
    const float* bf3    = (const float*)d_in[18];
    const float* Wf4    = (const float*)d_in[19];
    const float* bf4    = (const float*)d_in[20];
    float* out = (float*)d_out;

    const int n = NNODES;
    const int e = NEDGES;

    char* ws = (char*)d_ws;
    auto carve = [&](size_t bytes) -> void* {
        void* p = (void*)ws;
        ws += (bytes + 255) & ~(size_t)255;
        return p;
    };
    float* bufA    = (float*)carve((size_t)n * DP * 4);
    float* bufB    = (float*)carve((size_t)n * DP * 4);
    float* bufC    = (float*)carve((size_t)n * DP * 4);
    int*   hist    = (int*)carve((size_t)n * 4);
    int*   off     = (int*)carve((size_t)(n + 1) * 4);
    int*   cursor  = (int*)carve((size_t)n * 4);
    int*   partials= (int*)carve(512 * 4);
    int*   ssorted = (int*)carve((size_t)e * 4);
    float* dinv_sl = (float*)carve((size_t)n * 4);
    float* dinv_nsl= (float*)carve((size_t)n * 4);
    float* bnsum   = (float*)carve(DP * 4);
    float* bnsq    = (float*)carve(DP * 4);
    int*   gstart  = (int*)carve((size_t)(NGRAPH + 1) * 4);
    float* gpool   = (float*)carve((size_t)NGRAPH * DP * 4);

    const int nb = (n + 255) / 256;

    // ---- build CSR by dst ----
    hipMemsetAsync(hist, 0, (size_t)n * 4, stream);
    hist_kernel<<<(e + 255) / 256, 256, 0, stream>>>(dst, hist, e);
    dinv_kernel<<<(n + 255) / 256, 256, 0, stream>>>(hist, dinv_sl, dinv_nsl, n);
    scan1_kernel<<<nb, 256, 0, stream>>>(hist, off, partials, n);
    scan2_kernel<<<1, 512, 0, stream>>>(partials, nb);
    scan3_kernel<<<nb, 256, 0, stream>>>(off, partials, cursor, n, e);
    scatter_kernel<<<(e + 255) / 256, 256, 0, stream>>>(src, dst, cursor, ssorted, e);
    gbounds_kernel<<<1, 512, 0, stream>>>(batch, gstart, n);

    const int prop_blocks = (n + 3) / 4;
    const int mm_blocks = (n + 63) / 64;

    // ---- SGConv 1 ----
    prescale_kernel<<<(int)(((long)n * 32 + 255) / 256), 256, 0, stream>>>(x, dinv_sl, bufC, n);
    prop_kernel<<<prop_blocks, 256, 0, stream>>>(bufC, ssorted, off, dinv_sl, bufA, n, 1);
    matmul_kernel<<<mm_blocks, 256, 0, stream>>>(bufA, W1, b1, nullptr, dinv_sl, bufB, n, 128, DIM, 1);

    // ---- SGConv 2 ----
    prop_kernel<<<prop_blocks, 256, 0, stream>>>(bufB, ssorted, off, dinv_sl, bufA, n, 1);
    matmul_kernel<<<mm_blocks, 256, 0, stream>>>(bufA, W2, b2, nullptr, nullptr, bufB, n, DIM, DIM, 1);

    // ---- BatchNorm ----
    hipMemsetAsync(bnsum, 0, DP * 4, stream);
    hipMemsetAsync(bnsq, 0, DP * 4, stream);
    bn_stats_kernel<<<512, 128, 0, stream>>>(bufB, bnsum, bnsq, n);
    bn_apply_kernel<<<(int)(((long)n * DP + 255) / 256), 256, 0, stream>>>(bufB, bnsum, bnsq, gamma, beta, n);

    // ---- ARMAConv ----
    matmul_kernel<<<mm_blocks, 256, 0, stream>>>(bufB, Wa_init, nullptr, nullptr, dinv_nsl, bufA, n, DIM, DIM, 0);
    prop_kernel<<<prop_blocks, 256, 0, stream>>>(bufA, ssorted, off, dinv_nsl, bufC, n, 0);
    matmul_kernel<<<mm_blocks, 256, 0, stream>>>(bufB, Wa_root, ba, bufC, nullptr, bufA, n, DIM, DIM, 1);

    // ---- global add pool ----
    pool_kernel<<<NGRAPH, 512, 0, stream>>>(bufA, gstart, gpool);

    // ---- MLP head ----
    mlp_kernel<<<NGRAPH, 256, 0, stream>>>(gpool, Wf1, bf1, Wf2, bf2, Wf3, bf3, Wf4, bf4, out);
}

// Round 5
// 1009.300 us; speedup vs baseline: 1.6637x; 1.0557x over previous
//
#include <hip/hip_runtime.h>

#define NNODES 100000
#define NEDGES 1600000
#define NGRAPH 512
#define DIM    100
#define DP     128
#define EPSBN  1e-5f
#define NBUK   ((NNODES + 255) >> 8)   // 391 dst-buckets of 256 nodes
#define BINCH  8192                    // edges per bin block

// ---------------- degree histogram ----------------
__global__ void hist_kernel(const int* __restrict__ dst, int* __restrict__ hist, int e) {
    int i = blockIdx.x * blockDim.x + threadIdx.x;
    if (i < e) atomicAdd(&hist[dst[i]], 1);
}

// ---------------- dinv (with and without self loops) ----------------
__global__ void dinv_kernel(const int* __restrict__ hist, float* __restrict__ dsl,
                            float* __restrict__ dnsl, int n) {
    int i = blockIdx.x * blockDim.x + threadIdx.x;
    if (i >= n) return;
    float c = (float)hist[i];
    dsl[i]  = rsqrtf(c + 1.0f);
    dnsl[i] = (c > 0.0f) ? rsqrtf(c) : 0.0f;
}

// ---------------- two-level exclusive scan over hist (256/block) ----------------
__global__ void scan1_kernel(const int* __restrict__ hist, int* __restrict__ off,
                             int* __restrict__ partials, int n) {
    __shared__ int s[256];
    int i = blockIdx.x * 256 + threadIdx.x;
    int v = (i < n) ? hist[i] : 0;
    s[threadIdx.x] = v; __syncthreads();
    for (int o = 1; o < 256; o <<= 1) {
        int t = (threadIdx.x >= o) ? s[threadIdx.x - o] : 0;
        __syncthreads();
        s[threadIdx.x] += t;
        __syncthreads();
    }
    if (i < n) off[i] = s[threadIdx.x] - v;
    if (threadIdx.x == 255) partials[blockIdx.x] = s[255];
}

__global__ void scan2_kernel(int* __restrict__ partials, int nb) {
    __shared__ int s[512];
    int v = (threadIdx.x < nb) ? partials[threadIdx.x] : 0;
    s[threadIdx.x] = v; __syncthreads();
    for (int o = 1; o < 512; o <<= 1) {
        int t = (threadIdx.x >= o) ? s[threadIdx.x - o] : 0;
        __syncthreads();
        s[threadIdx.x] += t;
        __syncthreads();
    }
    if (threadIdx.x < nb) partials[threadIdx.x] = s[threadIdx.x] - v;
}

__global__ void scan3_kernel(int* __restrict__ off, const int* __restrict__ partials,
                             int* __restrict__ bcursor, int n, int e_total) {
    int i = blockIdx.x * 256 + threadIdx.x;
    if (i < n) {
        int v = off[i] + partials[blockIdx.x];
        off[i] = v;
        if ((i & 255) == 0) bcursor[i >> 8] = v;   // bucket write cursors
    }
    if (i == 0) off[n] = e_total;
}

// ---------------- pass 1: bin (src,dst) pairs bucket-major with LDS staging ----------------
__global__ __launch_bounds__(256) void bin_kernel(
        const int* __restrict__ src, const int* __restrict__ dst,
        int* __restrict__ bcursor, int2* __restrict__ gpairs, int e) {
    __shared__ int2 lpairs[BINCH];          // 64 KB
    __shared__ int lcount[NBUK], lstart[NBUK], lcur[NBUK], gbase[NBUK];
    int tid = threadIdx.x;
    int base = blockIdx.x * BINCH;
    int m = e - base; if (m > BINCH) m = BINCH;

    for (int b = tid; b < NBUK; b += 256) lcount[b] = 0;
    __syncthreads();

    // count
    for (int j = tid; j < m; j += 256)
        atomicAdd(&lcount[dst[base + j] >> 8], 1);
    __syncthreads();

    // serial exclusive scan (391 entries, thread 0)
    if (tid == 0) {
        int acc = 0;
        for (int b = 0; b < NBUK; b++) {
            lstart[b] = acc;
            lcur[b] = acc;
            acc += lcount[b];
        }
    }
    __syncthreads();

    // reserve global space per bucket (parallel atomics) + stage pairs into LDS
    for (int b = tid; b < NBUK; b += 256)
        gbase[b] = atomicAdd(&bcursor[b], lcount[b]);
    for (int j = tid; j < m; j += 256) {
        int s = src[base + j], d = dst[base + j];
        int p = atomicAdd(&lcur[d >> 8], 1);
        lpairs[p] = make_int2(s, d);
    }
    __syncthreads();

    // flush bucket-major (consecutive slots -> consecutive global addresses)
    for (int j = tid; j < m; j += 256) {
        int2 pr = lpairs[j];
        int b = pr.y >> 8;
        gpairs[gbase[b] + (j - lstart[b])] = pr;
    }
}

// ---------------- pass 2: within-bucket scatter, LDS cursors, L2-local writes ----------------
__global__ __launch_bounds__(256) void bucket_scatter_kernel(
        const int2* __restrict__ gpairs, const int* __restrict__ off,
        int* __restrict__ ssorted, int n) {
    __shared__ int cur[256];
    int b = blockIdx.x, tid = threadIdx.x;
    int node0 = b << 8;
    int nn = n - node0; if (nn > 256) nn = 256;
    if (tid < nn) cur[tid] = off[node0 + tid];
    __syncthreads();
    int e0 = off[node0];
    int e1 = off[(node0 + nn < n) ? node0 + nn : n];
    for (int j = e0 + tid; j < e1; j += 256) {
        int2 pr = gpairs[j];
        int p = atomicAdd(&cur[pr.y & 255], 1);
        ssorted[p] = pr.x;
    }
}

// ---------------- prescale rows: y[i,:] = x[i,:] * d[i] ----------------
__global__ void prescale_kernel(const float* __restrict__ x, const float* __restrict__ d,
                                float* __restrict__ y, int n) {
    long i = (long)blockIdx.x * blockDim.x + threadIdx.x;
    if (i >= (long)n * 32) return;
    int row = (int)(i >> 5);
    float s = d[row];
    float4 v = ((const float4*)x)[i];
    v.x *= s; v.y *= s; v.z *= s; v.w *= s;
    ((float4*)y)[i] = v;
}

// ---------------- propagation: one wave per node, prescaled input ----------------
__global__ __launch_bounds__(256) void prop_kernel(
        const float* __restrict__ pre, const int* __restrict__ ssorted,
        const int* __restrict__ off, const float* __restrict__ dinv,
        float* __restrict__ out, int n, int selfloop) {
    int wave = (blockIdx.x * blockDim.x + threadIdx.x) >> 6;
    int lane = threadIdx.x & 63;
    if (wave >= n) return;
    int e0 = off[wave], e1 = off[wave + 1];
    int deg = e1 - e0;
    int half = lane >> 5;
    int l32  = lane & 31;
    int c0 = l32 * 4;

    float4 acc = make_float4(0.f, 0.f, 0.f, 0.f);

    for (int base = 0; base < deg; base += 64) {
        int m = deg - base; if (m > 64) m = 64;
        int sidx = (lane < m) ? ssorted[e0 + base + lane] : 0;
        int j = 0;
        for (; j + 4 <= m; j += 4) {
            int sA = __shfl(sidx, j + half);
            int sB = __shfl(sidx, j + 2 + half);
            float4 vA = *(const float4*)&pre[(long)sA * DP + c0];
            float4 vB = *(const float4*)&pre[(long)sB * DP + c0];
            acc.x += vA.x + vB.x; acc.y += vA.y + vB.y;
            acc.z += vA.z + vB.z; acc.w += vA.w + vB.w;
        }
        for (; j + 2 <= m; j += 2) {
            int s = __shfl(sidx, j + half);
            float4 v = *(const float4*)&pre[(long)s * DP + c0];
            acc.x += v.x; acc.y += v.y; acc.z += v.z; acc.w += v.w;
        }
        if (j < m) {
            int s = __shfl(sidx, j);
            if (half == 0) {
                float4 v = *(const float4*)&pre[(long)s * DP + c0];
                acc.x += v.x; acc.y += v.y; acc.z += v.z; acc.w += v.w;
            }
        }
    }

    acc.x += __shfl(acc.x, l32 + 32);
    acc.y += __shfl(acc.y, l32 + 32);
    acc.z += __shfl(acc.z, l32 + 32);
    acc.w += __shfl(acc.w, l32 + 32);

    if (half == 0) {
        float dn = dinv[wave];
        if (selfloop) {
            float4 sv = *(const float4*)&pre[(long)wave * DP + c0];
            acc.x += sv.x; acc.y += sv.y; acc.z += sv.z; acc.w += sv.w;
        }
        float4 r;
        r.x = dn * acc.x; r.y = dn * acc.y; r.z = dn * acc.z; r.w = dn * acc.w;
        *(float4*)&out[(long)wave * DP + c0] = r;
    }
}

// ---------------- node-level matmul: A-tile in LDS (32 KB), W from L2 ----------------
__global__ __launch_bounds__(256) void matmul_kernel(
        const float* __restrict__ A, const float* __restrict__ W,
        const float* __restrict__ bias, const float* __restrict__ addend,
        const float* __restrict__ rowscale,
        float* __restrict__ C, int M, int K, int Kout, int relu) {
    __shared__ float Al[64 * DP];
    int tid = threadIdx.x;
    long row0blk = (long)blockIdx.x * 64;

    {
        const float4* Ag = (const float4*)A;
        float4* As = (float4*)Al;
        for (int j = tid; j < 64 * 32; j += 256) {
            long gr = row0blk + (j >> 5);
            if (gr >= M) gr = M - 1;
            As[j] = Ag[gr * 32 + (j & 31)];
        }
    }
    __syncthreads();

    int colg = tid & 31;
    int rowg = tid >> 5;
    int c0 = colg * 4;
    bool cvalid = (c0 < Kout);
    long row0 = row0blk + rowg * 8;

    float4 acc[8];
#pragma unroll
    for (int i = 0; i < 8; i++) acc[i] = make_float4(0.f, 0.f, 0.f, 0.f);

    const float4 z4 = make_float4(0.f, 0.f, 0.f, 0.f);
#pragma unroll 2
    for (int k = 0; k < K; k += 4) {
        float4 w0 = cvalid ? *(const float4*)&W[(k + 0) * Kout + c0] : z4;
        float4 w1 = cvalid ? *(const float4*)&W[(k + 1) * Kout + c0] : z4;
        float4 w2 = cvalid ? *(const float4*)&W[(k + 2) * Kout + c0] : z4;
        float4 w3 = cvalid ? *(const float4*)&W[(k + 3) * Kout + c0] : z4;
#pragma unroll
        for (int i = 0; i < 8; i++) {
            float4 a4 = *(const float4*)&Al[(rowg * 8 + i) * DP + k];
            acc[i].x += a4.x * w0.x + a4.y * w1.x + a4.z * w2.x + a4.w * w3.x;
            acc[i].y += a4.x * w0.y + a4.y * w1.y + a4.z * w2.y + a4.w * w3.y;
            acc[i].z += a4.x * w0.z + a4.y * w1.z + a4.z * w2.z + a4.w * w3.z;
            acc[i].w += a4.x * w0.w + a4.y * w1.w + a4.z * w2.w + a4.w * w3.w;
        }
    }

    float4 bv = make_float4(0.f, 0.f, 0.f, 0.f);
    if (bias && cvalid) bv = *(const float4*)&bias[c0];

#pragma unroll
    for (int i = 0; i < 8; i++) {
        long rr = row0 + i;
        if (rr >= M) break;
        float4 v = acc[i];
        v.x += bv.x; v.y += bv.y; v.z += bv.z; v.w += bv.w;
        if (addend) {
            float4 ad = *(const float4*)&addend[rr * DP + c0];
            v.x += ad.x; v.y += ad.y; v.z += ad.z; v.w += ad.w;
        }
        if (relu) {
            v.x = fmaxf(v.x, 0.f); v.y = fmaxf(v.y, 0.f);
            v.z = fmaxf(v.z, 0.f); v.w = fmaxf(v.w, 0.f);
        }
        if (rowscale) {
            float rs = rowscale[rr];
            v.x *= rs; v.y *= rs; v.z *= rs; v.w *= rs;
        }
        *(float4*)&C[rr * DP + c0] = v;
    }
}

// ---------------- batchnorm stats ----------------
__global__ void bn_stats_kernel(const float* __restrict__ h, float* __restrict__ sum,
                                float* __restrict__ sq, int n) {
    int col = threadIdx.x;
    float s = 0.f, q = 0.f;
    for (int row = blockIdx.x; row < n; row += gridDim.x) {
        float v = h[(long)row * DP + col];
        s += v;
        q += v * v;
    }
    atomicAdd(&sum[col], s);
    atomicAdd(&sq[col], q);
}

__global__ void bn_apply_kernel(float* __restrict__ h, const float* __restrict__ sum,
                                const float* __restrict__ sq, const float* __restrict__ gamma,
                                const float* __restrict__ beta, int n) {
    long i = (long)blockIdx.x * blockDim.x + threadIdx.x;
    if (i >= (long)n * DP) return;
    int c = (int)(i & 127);
    if (c >= DIM) return;
    float inv_n = 1.0f / (float)n;
    float mu = sum[c] * inv_n;
    float var = sq[c] * inv_n - mu * mu;
    float rs = rsqrtf(var + EPSBN);
    h[i] = (h[i] - mu) * rs * gamma[c] + beta[c];
}

// ---------------- graph boundaries (batch is sorted) ----------------
__global__ void gbounds_kernel(const int* __restrict__ batch, int* __restrict__ gstart, int n) {
    int g = threadIdx.x;
    int lo = 0, hi = n;
    while (lo < hi) {
        int mid = (lo + hi) >> 1;
        if (batch[mid] < g) lo = mid + 1; else hi = mid;
    }
    gstart[g] = lo;
    if (g == 0) gstart[NGRAPH] = n;
}

// ---------------- global add pool ----------------
__global__ __launch_bounds__(512) void pool_kernel(const float* __restrict__ a,
                                                   const int* __restrict__ gstart,
                                                   float* __restrict__ g) {
    __shared__ float red[512];
    int b = blockIdx.x, tid = threadIdx.x;
    int col = tid & 127;
    int quarter = tid >> 7;
    int lo = gstart[b], hi = gstart[b + 1];
    float s = 0.f;
    for (int r = lo + quarter; r < hi; r += 4)
        s += a[(long)r * DP + col];
    red[tid] = s;
    __syncthreads();
    if (tid < 128)
        g[b * DP + tid] = red[tid] + red[tid + 128] + red[tid + 256] + red[tid + 384];
}

// ---------------- fused MLP head ----------------
__global__ __launch_bounds__(256) void mlp_kernel(
        const float* __restrict__ g,
        const float* __restrict__ Wf1, const float* __restrict__ bf1,
        const float* __restrict__ Wf2, const float* __restrict__ bf2,
        const float* __restrict__ Wf3, const float* __restrict__ bf3,
        const float* __restrict__ Wf4, const float* __restrict__ bf4,
        float* __restrict__ out) {
    __shared__ float a0[100], a1[200], a2[300], a3[200], red[256];
    int b = blockIdx.x, tid = threadIdx.x;
    if (tid < 100) a0[tid] = g[b * DP + tid];
    __syncthreads();
    for (int c = tid; c < 200; c += 256) {
        float s = bf1[c];
        for (int k = 0; k < 100; k++) s += a0[k] * Wf1[k * 200 + c];
        a1[c] = fmaxf(s, 0.f);
    }
    __syncthreads();
    for (int c = tid; c < 300; c += 256) {
        float s = bf2[c];
        for (int k = 0; k < 200; k++) s += a1[k] * Wf2[k * 300 + c];
        a2[c] = fmaxf(s, 0.f);
    }
    __syncthreads();
    for (int c = tid; c < 200; c += 256) {
        float s = bf3[c];
        for (int k = 0; k < 300; k++) s += a2[k] * Wf3[k * 200 + c];
        a3[c] = fmaxf(s, 0.f);
    }
    __syncthreads();
    red[tid] = (tid < 200) ? a3[tid] * Wf4[tid] : 0.f;
    __syncthreads();
    for (int o = 128; o > 0; o >>= 1) {
        if (tid < o) red[tid] += red[tid + o];
        __syncthreads();
    }
    if (tid == 0) out[b] = red[0] + bf4[0];
}

extern "C" void kernel_launch(void* const* d_in, const int* in_sizes, int n_in,
                              void* d_out, int out_size, void* d_ws, size_t ws_size,
                              hipStream_t stream) {
    const float* x      = (const float*)d_in[0];
    const int*   src    = (const int*)d_in[1];
    const int*   dst    = (const int*)d_in[2];
    const int*   batch  = (const int*)d_in[3];
    const float* W1     = (const float*)d_in[4];
    const float* b1     = (const float*)d_in[5];
    const float* W2     = (const float*)d_in[6];
    const float* b2     = (const float*)d_in[7];
    const float* gamma  = (const float*)d_in[8];
    const float* beta   = (const float*)d_in[9];
    const float* Wa_init= (const float*)d_in[10];
    const float* Wa_root= (const float*)d_in[11];
    const float* ba     = (const float*)d_in[12];
    const float* Wf1    = (const float*)d_in[13];
    const float* bf1    = (const float*)d_in[14];
    const float* Wf2    = (const float*)d_in[15];
    const float* bf2    = (const float*)d_in[16];
    const float* Wf3    = (const float*)d_in[17];
    const float* bf3    = (const float*)d_in[18];
    const float* Wf4    = (const float*)d_in[19];
    const float* bf4    = (const float*)d_in[20];
    float* out = (float*)d_out;

    const int n = NNODES;
    const int e = NEDGES;

    char* ws = (char*)d_ws;
    auto carve = [&](size_t bytes) -> void* {
        void* p = (void*)ws;
        ws += (bytes + 255) & ~(size_t)255;
        return p;
    };
    float* bufA    = (float*)carve((size_t)n * DP * 4);
    float* bufB    = (float*)carve((size_t)n * DP * 4);
    float* bufC    = (float*)carve((size_t)n * DP * 4);
    int*   hist    = (int*)carve((size_t)n * 4);
    int*   off     = (int*)carve((size_t)(n + 1) * 4);
    int*   bcursor = (int*)carve((size_t)NBUK * 4);
    int*   partials= (int*)carve(512 * 4);
    int*   ssorted = (int*)carve((size_t)e * 4);
    int2*  gpairs  = (int2*)carve((size_t)e * 8);
    float* dinv_sl = (float*)carve((size_t)n * 4);
    float* dinv_nsl= (float*)carve((size_t)n * 4);
    float* bnsum   = (float*)carve(DP * 4);
    float* bnsq    = (float*)carve(DP * 4);
    int*   gstart  = (int*)carve((size_t)(NGRAPH + 1) * 4);
    float* gpool   = (float*)carve((size_t)NGRAPH * DP * 4);

    const int nb = (n + 255) / 256;

    // ---- build CSR by dst (bucketed two-pass scatter) ----
    hipMemsetAsync(hist, 0, (size_t)n * 4, stream);
    hist_kernel<<<(e + 255) / 256, 256, 0, stream>>>(dst, hist, e);
    dinv_kernel<<<(n + 255) / 256, 256, 0, stream>>>(hist, dinv_sl, dinv_nsl, n);
    scan1_kernel<<<nb, 256, 0, stream>>>(hist, off, partials, n);
    scan2_kernel<<<1, 512, 0, stream>>>(partials, nb);
    scan3_kernel<<<nb, 256, 0, stream>>>(off, partials, bcursor, n, e);
    bin_kernel<<<(e + BINCH - 1) / BINCH, 256, 0, stream>>>(src, dst, bcursor, gpairs, e);
    bucket_scatter_kernel<<<NBUK, 256, 0, stream>>>(gpairs, off, ssorted, n);
    gbounds_kernel<<<1, 512, 0, stream>>>(batch, gstart, n);

    const int prop_blocks = (n + 3) / 4;
    const int mm_blocks = (n + 63) / 64;

    // ---- SGConv 1 ----
    prescale_kernel<<<(int)(((long)n * 32 + 255) / 256), 256, 0, stream>>>(x, dinv_sl, bufC, n);
    prop_kernel<<<prop_blocks, 256, 0, stream>>>(bufC, ssorted, off, dinv_sl, bufA, n, 1);
    matmul_kernel<<<mm_blocks, 256, 0, stream>>>(bufA, W1, b1, nullptr, dinv_sl, bufB, n, 128, DIM, 1);

    // ---- SGConv 2 ----
    prop_kernel<<<prop_blocks, 256, 0, stream>>>(bufB, ssorted, off, dinv_sl, bufA, n, 1);
    matmul_kernel<<<mm_blocks, 256, 0, stream>>>(bufA, W2, b2, nullptr, nullptr, bufB, n, DIM, DIM, 1);

    // ---- BatchNorm ----
    hipMemsetAsync(bnsum, 0, DP * 4, stream);
    hipMemsetAsync(bnsq, 0, DP * 4, stream);
    bn_stats_kernel<<<512, 128, 0, stream>>>(bufB, bnsum, bnsq, n);
    bn_apply_kernel<<<(int)(((long)n * DP + 255) / 256), 256, 0, stream>>>(bufB, bnsum, bnsq, gamma, beta, n);

    // ---- ARMAConv ----
    matmul_kernel<<<mm_blocks, 256, 0, stream>>>(bufB, Wa_init, nullptr, nullptr, dinv_nsl, bufA, n, DIM, DIM, 0);
    prop_kernel<<<prop_blocks, 256, 0, stream>>>(bufA, ssorted, off, dinv_nsl, bufC, n, 0);
    matmul_kernel<<<mm_blocks, 256, 0, stream>>>(bufB, Wa_root, ba, bufC, nullptr, bufA, n, DIM, DIM, 1);

    // ---- global add pool ----
    pool_kernel<<<NGRAPH, 512, 0, stream>>>(bufA, gstart, gpool);

    // ---- MLP head ----
    mlp_kernel<<<NGRAPH, 256, 0, stream>>>(gpool, Wf1, bf1, Wf2, bf2, Wf3, bf3, Wf4, bf4, out);
}

// Round 6
// 832.986 us; speedup vs baseline: 2.0159x; 1.2117x over previous
//
#include <hip/hip_runtime.h>
#include <hip/hip_fp16.h>

#define NNODES 100000
#define NEDGES 1600000
#define NGRAPH 512
#define DIM    100
#define DP     128
#define EPSBN  1e-5f
#define NBUK   ((NNODES + 255) >> 8)   // 391 dst-buckets of 256 nodes
#define BINCH  8192                    // edges per bin block

// ---------------- degree histogram ----------------
__global__ void hist_kernel(const int* __restrict__ dst, int* __restrict__ hist, int e) {
    int i = blockIdx.x * blockDim.x + threadIdx.x;
    if (i < e) atomicAdd(&hist[dst[i]], 1);
}

// ---------------- dinv ----------------
__global__ void dinv_kernel(const int* __restrict__ hist, float* __restrict__ dsl,
                            float* __restrict__ dnsl, int n) {
    int i = blockIdx.x * blockDim.x + threadIdx.x;
    if (i >= n) return;
    float c = (float)hist[i];
    dsl[i]  = rsqrtf(c + 1.0f);
    dnsl[i] = (c > 0.0f) ? rsqrtf(c) : 0.0f;
}

// ---------------- two-level exclusive scan ----------------
__global__ void scan1_kernel(const int* __restrict__ hist, int* __restrict__ off,
                             int* __restrict__ partials, int n) {
    __shared__ int s[256];
    int i = blockIdx.x * 256 + threadIdx.x;
    int v = (i < n) ? hist[i] : 0;
    s[threadIdx.x] = v; __syncthreads();
    for (int o = 1; o < 256; o <<= 1) {
        int t = (threadIdx.x >= o) ? s[threadIdx.x - o] : 0;
        __syncthreads();
        s[threadIdx.x] += t;
        __syncthreads();
    }
    if (i < n) off[i] = s[threadIdx.x] - v;
    if (threadIdx.x == 255) partials[blockIdx.x] = s[255];
}

__global__ void scan2_kernel(int* __restrict__ partials, int nb) {
    __shared__ int s[512];
    int v = (threadIdx.x < nb) ? partials[threadIdx.x] : 0;
    s[threadIdx.x] = v; __syncthreads();
    for (int o = 1; o < 512; o <<= 1) {
        int t = (threadIdx.x >= o) ? s[threadIdx.x - o] : 0;
        __syncthreads();
        s[threadIdx.x] += t;
        __syncthreads();
    }
    if (threadIdx.x < nb) partials[threadIdx.x] = s[threadIdx.x] - v;
}

__global__ void scan3_kernel(int* __restrict__ off, const int* __restrict__ partials,
                             int* __restrict__ bcursor, int n, int e_total) {
    int i = blockIdx.x * 256 + threadIdx.x;
    if (i < n) {
        int v = off[i] + partials[blockIdx.x];
        off[i] = v;
        if ((i & 255) == 0) bcursor[i >> 8] = v;
    }
    if (i == 0) off[n] = e_total;
}

// ---------------- pass 1: bin (src,dst) pairs bucket-major ----------------
__global__ __launch_bounds__(256) void bin_kernel(
        const int* __restrict__ src, const int* __restrict__ dst,
        int* __restrict__ bcursor, int2* __restrict__ gpairs, int e) {
    __shared__ int2 lpairs[BINCH];
    __shared__ int lcount[NBUK], lstart[NBUK], lcur[NBUK], gbase[NBUK];
    int tid = threadIdx.x;
    int base = blockIdx.x * BINCH;
    int m = e - base; if (m > BINCH) m = BINCH;

    for (int b = tid; b < NBUK; b += 256) lcount[b] = 0;
    __syncthreads();

    for (int j = tid; j < m; j += 256)
        atomicAdd(&lcount[dst[base + j] >> 8], 1);
    __syncthreads();

    if (tid == 0) {
        int acc = 0;
        for (int b = 0; b < NBUK; b++) {
            lstart[b] = acc;
            lcur[b] = acc;
            acc += lcount[b];
        }
    }
    __syncthreads();

    for (int b = tid; b < NBUK; b += 256)
        gbase[b] = atomicAdd(&bcursor[b], lcount[b]);
    for (int j = tid; j < m; j += 256) {
        int s = src[base + j], d = dst[base + j];
        int p = atomicAdd(&lcur[d >> 8], 1);
        lpairs[p] = make_int2(s, d);
    }
    __syncthreads();

    for (int j = tid; j < m; j += 256) {
        int2 pr = lpairs[j];
        int b = pr.y >> 8;
        gpairs[gbase[b] + (j - lstart[b])] = pr;
    }
}

// ---------------- pass 2: within-bucket scatter ----------------
__global__ __launch_bounds__(256) void bucket_scatter_kernel(
        const int2* __restrict__ gpairs, const int* __restrict__ off,
        int* __restrict__ ssorted, int n) {
    __shared__ int cur[256];
    int b = blockIdx.x, tid = threadIdx.x;
    int node0 = b << 8;
    int nn = n - node0; if (nn > 256) nn = 256;
    if (tid < nn) cur[tid] = off[node0 + tid];
    __syncthreads();
    int e0 = off[node0];
    int e1 = off[(node0 + nn < n) ? node0 + nn : n];
    for (int j = e0 + tid; j < e1; j += 256) {
        int2 pr = gpairs[j];
        int p = atomicAdd(&cur[pr.y & 255], 1);
        ssorted[p] = pr.x;
    }
}

// ---------------- prescale rows to fp16: yh[i,:] = (half)(x[i,:] * d[i]) ----------------
__global__ void prescale_kernel(const float* __restrict__ x, const float* __restrict__ d,
                                __half* __restrict__ yh, int n) {
    long i = (long)blockIdx.x * blockDim.x + threadIdx.x;   // one float4 -> half4 per thread
    if (i >= (long)n * 32) return;
    int row = (int)(i >> 5);
    float s = d[row];
    float4 v = ((const float4*)x)[i];
    __half2 p01 = __floats2half2_rn(v.x * s, v.y * s);
    __half2 p23 = __floats2half2_rn(v.z * s, v.w * s);
    uint2 u;
    u.x = *(unsigned int*)&p01;
    u.y = *(unsigned int*)&p23;
    ((uint2*)yh)[i] = u;
}

// ---------------- propagation: one wave per node, fp16 rows, fp32 accumulate ----------------
__global__ __launch_bounds__(256) void prop_kernel(
        const __half* __restrict__ pre, const int* __restrict__ ssorted,
        const int* __restrict__ off, const float* __restrict__ dinv,
        float* __restrict__ out, int n, int selfloop) {
    int wave = (blockIdx.x * blockDim.x + threadIdx.x) >> 6;
    int lane = threadIdx.x & 63;
    if (wave >= n) return;
    int e0 = off[wave], e1 = off[wave + 1];
    int deg = e1 - e0;
    int half_id = lane >> 5;
    int l32  = lane & 31;
    int c0 = l32 * 4;            // 32 lanes x 4 halves = 128 cols

    float4 acc = make_float4(0.f, 0.f, 0.f, 0.f);

    auto addrow = [&](int s, float4& a) {
        uint2 u = *(const uint2*)&pre[(long)s * DP + c0];
        __half2 h01 = *(__half2*)&u.x;
        __half2 h23 = *(__half2*)&u.y;
        float2 f01 = __half22float2(h01);
        float2 f23 = __half22float2(h23);
        a.x += f01.x; a.y += f01.y; a.z += f23.x; a.w += f23.y;
    };

    for (int base = 0; base < deg; base += 64) {
        int m = deg - base; if (m > 64) m = 64;
        int sidx = (lane < m) ? ssorted[e0 + base + lane] : 0;
        int j = 0;
        for (; j + 8 <= m; j += 8) {       // 8 edges, 4 loads in flight per half-wave
            int sA = __shfl(sidx, j + half_id);
            int sB = __shfl(sidx, j + 2 + half_id);
            int sC = __shfl(sidx, j + 4 + half_id);
            int sD = __shfl(sidx, j + 6 + half_id);
            uint2 uA = *(const uint2*)&pre[(long)sA * DP + c0];
            uint2 uB = *(const uint2*)&pre[(long)sB * DP + c0];
            uint2 uC = *(const uint2*)&pre[(long)sC * DP + c0];
            uint2 uD = *(const uint2*)&pre[(long)sD * DP + c0];
            float2 a0 = __half22float2(*(__half2*)&uA.x), a1 = __half22float2(*(__half2*)&uA.y);
            float2 b0 = __half22float2(*(__half2*)&uB.x), b1 = __half22float2(*(__half2*)&uB.y);
            float2 c0f = __half22float2(*(__half2*)&uC.x), c1 = __half22float2(*(__half2*)&uC.y);
            float2 d0 = __half22float2(*(__half2*)&uD.x), d1 = __half22float2(*(__half2*)&uD.y);
            acc.x += (a0.x + b0.x) + (c0f.x + d0.x);
            acc.y += (a0.y + b0.y) + (c0f.y + d0.y);
            acc.z += (a1.x + b1.x) + (c1.x + d1.x);
            acc.w += (a1.y + b1.y) + (c1.y + d1.y);
        }
        for (; j + 2 <= m; j += 2) {
            int s = __shfl(sidx, j + half_id);
            addrow(s, acc);
        }
        if (j < m) {
            int s = __shfl(sidx, j);
            if (half_id == 0) addrow(s, acc);
        }
    }

    acc.x += __shfl(acc.x, l32 + 32);
    acc.y += __shfl(acc.y, l32 + 32);
    acc.z += __shfl(acc.z, l32 + 32);
    acc.w += __shfl(acc.w, l32 + 32);

    if (half_id == 0) {
        float dn = dinv[wave];
        if (selfloop) addrow(wave, acc);
        float4 r;
        r.x = dn * acc.x; r.y = dn * acc.y; r.z = dn * acc.z; r.w = dn * acc.w;
        *(float4*)&out[(long)wave * DP + c0] = r;
    }
}

// ---------------- node-level matmul: A-tile in LDS, W from L2, fp32 or fp16 out ----------------
__global__ __launch_bounds__(256) void matmul_kernel(
        const float* __restrict__ A, const float* __restrict__ W,
        const float* __restrict__ bias, const float* __restrict__ addend,
        const float* __restrict__ rowscale,
        float* __restrict__ C, __half* __restrict__ Ch,
        int M, int K, int Kout, int relu) {
    __shared__ float Al[64 * DP];
    int tid = threadIdx.x;
    long row0blk = (long)blockIdx.x * 64;

    {
        const float4* Ag = (const float4*)A;
        float4* As = (float4*)Al;
        for (int j = tid; j < 64 * 32; j += 256) {
            long gr = row0blk + (j >> 5);
            if (gr >= M) gr = M - 1;
            As[j] = Ag[gr * 32 + (j & 31)];
        }
    }
    __syncthreads();

    int colg = tid & 31;
    int rowg = tid >> 5;
    int c0 = colg * 4;
    bool cvalid = (c0 < Kout);
    long row0 = row0blk + rowg * 8;

    float4 acc[8];
#pragma unroll
    for (int i = 0; i < 8; i++) acc[i] = make_float4(0.f, 0.f, 0.f, 0.f);

    const float4 z4 = make_float4(0.f, 0.f, 0.f, 0.f);
#pragma unroll 2
    for (int k = 0; k < K; k += 4) {
        float4 w0 = cvalid ? *(const float4*)&W[(k + 0) * Kout + c0] : z4;
        float4 w1 = cvalid ? *(const float4*)&W[(k + 1) * Kout + c0] : z4;
        float4 w2 = cvalid ? *(const float4*)&W[(k + 2) * Kout + c0] : z4;
        float4 w3 = cvalid ? *(const float4*)&W[(k + 3) * Kout + c0] : z4;
#pragma unroll
        for (int i = 0; i < 8; i++) {
            float4 a4 = *(const float4*)&Al[(rowg * 8 + i) * DP + k];
            acc[i].x += a4.x * w0.x + a4.y * w1.x + a4.z * w2.x + a4.w * w3.x;
            acc[i].y += a4.x * w0.y + a4.y * w1.y + a4.z * w2.y + a4.w * w3.y;
            acc[i].z += a4.x * w0.z + a4.y * w1.z + a4.z * w2.z + a4.w * w3.z;
            acc[i].w += a4.x * w0.w + a4.y * w1.w + a4.z * w2.w + a4.w * w3.w;
        }
    }

    float4 bv = make_float4(0.f, 0.f, 0.f, 0.f);
    if (bias && cvalid) bv = *(const float4*)&bias[c0];

#pragma unroll
    for (int i = 0; i < 8; i++) {
        long rr = row0 + i;
        if (rr >= M) break;
        float4 v = acc[i];
        v.x += bv.x; v.y += bv.y; v.z += bv.z; v.w += bv.w;
        if (addend) {
            float4 ad = *(const float4*)&addend[rr * DP + c0];
            v.x += ad.x; v.y += ad.y; v.z += ad.z; v.w += ad.w;
        }
        if (relu) {
            v.x = fmaxf(v.x, 0.f); v.y = fmaxf(v.y, 0.f);
            v.z = fmaxf(v.z, 0.f); v.w = fmaxf(v.w, 0.f);
        }
        if (rowscale) {
            float rs = rowscale[rr];
            v.x *= rs; v.y *= rs; v.z *= rs; v.w *= rs;
        }
        if (Ch) {
            __half2 p01 = __floats2half2_rn(v.x, v.y);
            __half2 p23 = __floats2half2_rn(v.z, v.w);
            uint2 u;
            u.x = *(unsigned int*)&p01;
            u.y = *(unsigned int*)&p23;
            *(uint2*)&Ch[rr * DP + c0] = u;
        } else {
            *(float4*)&C[rr * DP + c0] = v;
        }
    }
}

// ---------------- batchnorm stats ----------------
__global__ void bn_stats_kernel(const float* __restrict__ h, float* __restrict__ sum,
                                float* __restrict__ sq, int n) {
    int col = threadIdx.x;
    float s = 0.f, q = 0.f;
    for (int row = blockIdx.x; row < n; row += gridDim.x) {
        float v = h[(long)row * DP + col];
        s += v;
        q += v * v;
    }
    atomicAdd(&sum[col], s);
    atomicAdd(&sq[col], q);
}

__global__ void bn_apply_kernel(float* __restrict__ h, const float* __restrict__ sum,
                                const float* __restrict__ sq, const float* __restrict__ gamma,
                                const float* __restrict__ beta, int n) {
    long i = (long)blockIdx.x * blockDim.x + threadIdx.x;
    if (i >= (long)n * DP) return;
    int c = (int)(i & 127);
    if (c >= DIM) return;
    float inv_n = 1.0f / (float)n;
    float mu = sum[c] * inv_n;
    float var = sq[c] * inv_n - mu * mu;
    float rs = rsqrtf(var + EPSBN);
    h[i] = (h[i] - mu) * rs * gamma[c] + beta[c];
}

// ---------------- graph boundaries ----------------
__global__ void gbounds_kernel(const int* __restrict__ batch, int* __restrict__ gstart, int n) {
    int g = threadIdx.x;
    int lo = 0, hi = n;
    while (lo < hi) {
        int mid = (lo + hi) >> 1;
        if (batch[mid] < g) lo = mid + 1; else hi = mid;
    }
    gstart[g] = lo;
    if (g == 0) gstart[NGRAPH] = n;
}

// ---------------- global add pool ----------------
__global__ __launch_bounds__(512) void pool_kernel(const float* __restrict__ a,
                                                   const int* __restrict__ gstart,
                                                   float* __restrict__ g) {
    __shared__ float red[512];
    int b = blockIdx.x, tid = threadIdx.x;
    int col = tid & 127;
    int quarter = tid >> 7;
    int lo = gstart[b], hi = gstart[b + 1];
    float s = 0.f;
    for (int r = lo + quarter; r < hi; r += 4)
        s += a[(long)r * DP + col];
    red[tid] = s;
    __syncthreads();
    if (tid < 128)
        g[b * DP + tid] = red[tid] + red[tid + 128] + red[tid + 256] + red[tid + 384];
}

// ---------------- fused MLP head ----------------
__global__ __launch_bounds__(256) void mlp_kernel(
        const float* __restrict__ g,
        const float* __restrict__ Wf1, const float* __restrict__ bf1,
        const float* __restrict__ Wf2, const float* __restrict__ bf2,
        const float* __restrict__ Wf3, const float* __restrict__ bf3,
        const float* __restrict__ Wf4, const float* __restrict__ bf4,
        float* __restrict__ out) {
    __shared__ float a0[100], a1[200], a2[300], a3[200], red[256];
    int b = blockIdx.x, tid = threadIdx.x;
    if (tid < 100) a0[tid] = g[b * DP + tid];
    __syncthreads();
    for (int c = tid; c < 200; c += 256) {
        float s = bf1[c];
        for (int k = 0; k < 100; k++) s += a0[k] * Wf1[k * 200 + c];
        a1[c] = fmaxf(s, 0.f);
    }
    __syncthreads();
    for (int c = tid; c < 300; c += 256) {
        float s = bf2[c];
        for (int k = 0; k < 200; k++) s += a1[k] * Wf2[k * 300 + c];
        a2[c] = fmaxf(s, 0.f);
    }
    __syncthreads();
    for (int c = tid; c < 200; c += 256) {
        float s = bf3[c];
        for (int k = 0; k < 300; k++) s += a2[k] * Wf3[k * 200 + c];
        a3[c] = fmaxf(s, 0.f);
    }
    __syncthreads();
    red[tid] = (tid < 200) ? a3[tid] * Wf4[tid] : 0.f;
    __syncthreads();
    for (int o = 128; o > 0; o >>= 1) {
        if (tid < o) red[tid] += red[tid + o];
        __syncthreads();
    }
    if (tid == 0) out[b] = red[0] + bf4[0];
}

extern "C" void kernel_launch(void* const* d_in, const int* in_sizes, int n_in,
                              void* d_out, int out_size, void* d_ws, size_t ws_size,
                              hipStream_t stream) {
    const float* x      = (const float*)d_in[0];
    const int*   src    = (const int*)d_in[1];
    const int*   dst    = (const int*)d_in[2];
    const int*   batch  = (const int*)d_in[3];
    const float* W1     = (const float*)d_in[4];
    const float* b1     = (const float*)d_in[5];
    const float* W2     = (const float*)d_in[6];
    const float* b2     = (const float*)d_in[7];
    const float* gamma  = (const float*)d_in[8];
    const float* beta   = (const float*)d_in[9];
    const float* Wa_init= (const float*)d_in[10];
    const float* Wa_root= (const float*)d_in[11];
    const float* ba     = (const float*)d_in[12];
    const float* Wf1    = (const float*)d_in[13];
    const float* bf1    = (const float*)d_in[14];
    const float* Wf2    = (const float*)d_in[15];
    const float* bf2    = (const float*)d_in[16];
    const float* Wf3    = (const float*)d_in[17];
    const float* bf3    = (const float*)d_in[18];
    const float* Wf4    = (const float*)d_in[19];
    const float* bf4    = (const float*)d_in[20];
    float* out = (float*)d_out;

    const int n = NNODES;
    const int e = NEDGES;

    char* ws = (char*)d_ws;
    auto carve = [&](size_t bytes) -> void* {
        void* p = (void*)ws;
        ws += (bytes + 255) & ~(size_t)255;
        return p;
    };
    float*  bufA    = (float*)carve((size_t)n * DP * 4);
    float*  bufB    = (float*)carve((size_t)n * DP * 4);
    float*  bufC    = (float*)carve((size_t)n * DP * 4);
    __half* bufH    = (__half*)carve((size_t)n * DP * 2);
    int*    hist    = (int*)carve((size_t)n * 4);
    int*    off     = (int*)carve((size_t)(n + 1) * 4);
    int*    bcursor = (int*)carve((size_t)NBUK * 4);
    int*    partials= (int*)carve(512 * 4);
    int*    ssorted = (int*)carve((size_t)e * 4);
    int2*   gpairs  = (int2*)carve((size_t)e * 8);
    float*  dinv_sl = (float*)carve((size_t)n * 4);
    float*  dinv_nsl= (float*)carve((size_t)n * 4);
    float*  bnsum   = (float*)carve(DP * 4);
    float*  bnsq    = (float*)carve(DP * 4);
    int*    gstart  = (int*)carve((size_t)(NGRAPH + 1) * 4);
    float*  gpool   = (float*)carve((size_t)NGRAPH * DP * 4);

    const int nb = (n + 255) / 256;

    // ---- build CSR by dst (bucketed two-pass scatter) ----
    hipMemsetAsync(hist, 0, (size_t)n * 4, stream);
    hist_kernel<<<(e + 255) / 256, 256, 0, stream>>>(dst, hist, e);
    dinv_kernel<<<(n + 255) / 256, 256, 0, stream>>>(hist, dinv_sl, dinv_nsl, n);
    scan1_kernel<<<nb, 256, 0, stream>>>(hist, off, partials, n);
    scan2_kernel<<<1, 512, 0, stream>>>(partials, nb);
    scan3_kernel<<<nb, 256, 0, stream>>>(off, partials, bcursor, n, e);
    bin_kernel<<<(e + BINCH - 1) / BINCH, 256, 0, stream>>>(src, dst, bcursor, gpairs, e);
    bucket_scatter_kernel<<<NBUK, 256, 0, stream>>>(gpairs, off, ssorted, n);
    gbounds_kernel<<<1, 512, 0, stream>>>(batch, gstart, n);

    const int prop_blocks = (n + 3) / 4;
    const int mm_blocks = (n + 63) / 64;

    // ---- SGConv 1: pre(fp16) = x*dinv; prop; h1' = relu(prop@W1+b1)*dinv -> fp16 ----
    prescale_kernel<<<(int)(((long)n * 32 + 255) / 256), 256, 0, stream>>>(x, dinv_sl, bufH, n);
    prop_kernel<<<prop_blocks, 256, 0, stream>>>(bufH, ssorted, off, dinv_sl, bufA, n, 1);
    matmul_kernel<<<mm_blocks, 256, 0, stream>>>(bufA, W1, b1, nullptr, dinv_sl, nullptr, bufH, n, 128, DIM, 1);

    // ---- SGConv 2: prop on fp16 h1'; h2 = relu(prop@W2+b2) (fp32, BN needs it) ----
    prop_kernel<<<prop_blocks, 256, 0, stream>>>(bufH, ssorted, off, dinv_sl, bufA, n, 1);
    matmul_kernel<<<mm_blocks, 256, 0, stream>>>(bufA, W2, b2, nullptr, nullptr, bufB, nullptr, n, DIM, DIM, 1);

    // ---- BatchNorm ----
    hipMemsetAsync(bnsum, 0, DP * 4, stream);
    hipMemsetAsync(bnsq, 0, DP * 4, stream);
    bn_stats_kernel<<<512, 128, 0, stream>>>(bufB, bnsum, bnsq, n);
    bn_apply_kernel<<<(int)(((long)n * DP + 255) / 256), 256, 0, stream>>>(bufB, bnsum, bnsq, gamma, beta, n);

    // ---- ARMAConv: t(fp16) = (h@Wa_init)*dinv_nsl ; prop(no SL) ; relu(h@Wa_root+ba+t_prop) ----
    matmul_kernel<<<mm_blocks, 256, 0, stream>>>(bufB, Wa_init, nullptr, nullptr, dinv_nsl, nullptr, bufH, n, DIM, DIM, 0);
    prop_kernel<<<prop_blocks, 256, 0, stream>>>(bufH, ssorted, off, dinv_nsl, bufC, n, 0);
    matmul_kernel<<<mm_blocks, 256, 0, stream>>>(bufB, Wa_root, ba, bufC, nullptr, bufA, nullptr, n, DIM, DIM, 1);

    // ---- global add pool ----
    pool_kernel<<<NGRAPH, 512, 0, stream>>>(bufA, gstart, gpool);

    // ---- MLP head ----
    mlp_kernel<<<NGRAPH, 256, 0, stream>>>(gpool, Wf1, bf1, Wf2, bf2, Wf3, bf3, Wf4, bf4, out);
}